// Round 6
// baseline (772.268 us; speedup 1.0000x reference)
//
#include <hip/hip_runtime.h>

#define TPB 256
#define HID 128
#define IN_C 4
#define SCAN_TPB 256
#define SCAN_CHUNK 1024   // 4 elements per thread

// ---------------------------------------------------------------------------
// K0: zero deg_i and out
__global__ void k_init(int* deg_i, float* out, int n, int outsz) {
    int i = blockIdx.x * blockDim.x + threadIdx.x;
    if (i < n) deg_i[i] = 0;
    if (i < outsz) out[i] = 0.0f;
}

// K1: in-degree histogram (int atomics, random dsts -> low contention)
__global__ void k_hist(const int* __restrict__ dst, int* deg_i, int e) {
    int i = blockIdx.x * blockDim.x + threadIdx.x;
    if (i < e) atomicAdd(&deg_i[dst[i]], 1);
}

// K2: per-graph node counts via binary search on sorted batch (no atomics)
__global__ void k_cnt(const int* __restrict__ batch, int* cnt, int n, int bg) {
    int b = blockIdx.x * blockDim.x + threadIdx.x;
    if (b >= bg) return;
    int lo0 = 0, hi0 = n;
    while (lo0 < hi0) { int m = (lo0 + hi0) >> 1; if (batch[m] < b) lo0 = m + 1; else hi0 = m; }
    int lo1 = lo0, hi1 = n;
    while (lo1 < hi1) { int m = (lo1 + hi1) >> 1; if (batch[m] < b + 1) lo1 = m + 1; else hi1 = m; }
    cnt[b] = lo1 - lo0;
}

// K3a: per-block sums of deg_i (block = SCAN_CHUNK elements)
__global__ __launch_bounds__(SCAN_TPB) void k_scan_part(const int* __restrict__ deg_i,
                                                        int* bsum, int n) {
    __shared__ int red[SCAN_TPB];
    int b = blockIdx.x, t = threadIdx.x;
    int base = b * SCAN_CHUNK + t * 4;
    int s = 0;
#pragma unroll
    for (int k = 0; k < 4; k++) {
        int i = base + k;
        if (i < n) s += deg_i[i];
    }
    red[t] = s;
    __syncthreads();
    for (int d = SCAN_TPB / 2; d > 0; d >>= 1) {
        if (t < d) red[t] += red[t + d];
        __syncthreads();
    }
    if (t == 0) bsum[b] = red[0];
}

// K3b: single-block exclusive scan of block sums
__global__ __launch_bounds__(1024) void k_scan_bsum(int* bsum, int nb) {
    __shared__ int red[1024];
    int t = threadIdx.x;
    int carry = 0;
    for (int base = 0; base < nb; base += 1024) {
        int i = base + t;
        int v = (i < nb) ? bsum[i] : 0;
        red[t] = v;
        __syncthreads();
        for (int d = 1; d < 1024; d <<= 1) {
            int x = 0;
            if (t >= d) x = red[t - d];
            __syncthreads();
            if (t >= d) red[t] += x;
            __syncthreads();
        }
        int tot = red[1023];
        if (i < nb) bsum[i] = carry + red[t] - v;   // exclusive
        carry += tot;
        __syncthreads();
    }
}

// K3c: final scan pass -> off, cursor; fused dinv = rsqrt(deg+1)
__global__ __launch_bounds__(SCAN_TPB) void k_scan_final(
        const int* __restrict__ deg_i, const int* __restrict__ bsum,
        int* off, int* cursor, float* dinv, int n, int e) {
    __shared__ int red[SCAN_TPB];
    int b = blockIdx.x, t = threadIdx.x;
    int base = b * SCAN_CHUNK + t * 4;
    int v[4];
    int s = 0;
#pragma unroll
    for (int k = 0; k < 4; k++) {
        int i = base + k;
        v[k] = (i < n) ? deg_i[i] : 0;
        s += v[k];
    }
    red[t] = s;
    __syncthreads();
    for (int d = 1; d < SCAN_TPB; d <<= 1) {
        int x = 0;
        if (t >= d) x = red[t - d];
        __syncthreads();
        if (t >= d) red[t] += x;
        __syncthreads();
    }
    int run = bsum[b] + red[t] - s;
#pragma unroll
    for (int k = 0; k < 4; k++) {
        int i = base + k;
        if (i < n) {
            off[i] = run;
            cursor[i] = run;
            dinv[i] = rsqrtf((float)v[k] + 1.0f);
            run += v[k];
        }
    }
    if (b == 0 && t == 0) off[n] = e;
}

// K5: counting-sort fill: src_sorted grouped by dst
__global__ void k_fillpos(const int* __restrict__ src, const int* __restrict__ dst,
                          int* cursor, int* src_sorted, int e) {
    int i = blockIdx.x * blockDim.x + threadIdx.x;
    if (i >= e) return;
    int d = dst[i];
    int p = atomicAdd(&cursor[d], 1);
    src_sorted[p] = src[i];
}

// K6: layer-1 propagation as gather on raw 4-channel x; unroll x4 for MLP
__global__ void k_gather1(const int* __restrict__ off, const int* __restrict__ src_sorted,
                          const float* __restrict__ dinv, const float* __restrict__ x,
                          float* xp, int n) {
    int v = blockIdx.x * blockDim.x + threadIdx.x;
    if (v >= n) return;
    float dv = dinv[v];
    const float4* x4 = (const float4*)x;
    float4 xv = x4[v];
    float sl = dv * dv;
    float4 A = make_float4(sl * xv.x, sl * xv.y, sl * xv.z, sl * xv.w);
    float4 B = make_float4(0.f, 0.f, 0.f, 0.f);
    float4 C = make_float4(0.f, 0.f, 0.f, 0.f);
    float4 D = make_float4(0.f, 0.f, 0.f, 0.f);
    int e0 = off[v], e1 = off[v + 1];
    int e = e0;
    for (; e + 4 <= e1; e += 4) {
        int s0 = src_sorted[e], s1 = src_sorted[e + 1];
        int s2 = src_sorted[e + 2], s3 = src_sorted[e + 3];
        float n0 = dinv[s0] * dv, n1 = dinv[s1] * dv;
        float n2 = dinv[s2] * dv, n3 = dinv[s3] * dv;
        float4 r0 = x4[s0], r1 = x4[s1], r2 = x4[s2], r3 = x4[s3];
        A.x = fmaf(n0, r0.x, A.x); A.y = fmaf(n0, r0.y, A.y);
        A.z = fmaf(n0, r0.z, A.z); A.w = fmaf(n0, r0.w, A.w);
        B.x = fmaf(n1, r1.x, B.x); B.y = fmaf(n1, r1.y, B.y);
        B.z = fmaf(n1, r1.z, B.z); B.w = fmaf(n1, r1.w, B.w);
        C.x = fmaf(n2, r2.x, C.x); C.y = fmaf(n2, r2.y, C.y);
        C.z = fmaf(n2, r2.z, C.z); C.w = fmaf(n2, r2.w, C.w);
        D.x = fmaf(n3, r3.x, D.x); D.y = fmaf(n3, r3.y, D.y);
        D.z = fmaf(n3, r3.z, D.z); D.w = fmaf(n3, r3.w, D.w);
    }
    for (; e < e1; e++) {
        int s = src_sorted[e];
        float nm = dinv[s] * dv;
        float4 r = x4[s];
        A.x = fmaf(nm, r.x, A.x); A.y = fmaf(nm, r.y, A.y);
        A.z = fmaf(nm, r.z, A.z); A.w = fmaf(nm, r.w, A.w);
    }
    float4 o;
    o.x = (A.x + B.x) + (C.x + D.x);
    o.y = (A.y + B.y) + (C.y + D.y);
    o.z = (A.z + B.z) + (C.z + D.z);
    o.w = (A.w + B.w) + (C.w + D.w);
    ((float4*)xp)[v] = o;
}

// K7: f1 = relu(xp @ W1 + b1)
__global__ void k_f1(const float* __restrict__ xp, const float* __restrict__ W1,
                     const float* __restrict__ b1, float* f1, int n) {
    int i = blockIdx.x * blockDim.x + threadIdx.x;
    if (i >= n * HID) return;
    int v = i >> 7, c = i & (HID - 1);
    const float4* xr = (const float4*)(xp + v * IN_C);
    float4 xv = *xr;
    float s = fmaf(xv.x, W1[c],
              fmaf(xv.y, W1[HID + c],
              fmaf(xv.z, W1[2 * HID + c],
              fmaf(xv.w, W1[3 * HID + c], b1[c]))));
    f1[i] = s > 0.0f ? s : 0.0f;
}

// K8: layer-2 gather: one WAVE per node, float2 per lane, x4 unrolled MLP
__global__ __launch_bounds__(256) void k_gather2(
        const int* __restrict__ off, const int* __restrict__ src_sorted,
        const float* __restrict__ dinv, const float* __restrict__ f1,
        float* acc2, int n) {
    int wv = threadIdx.x >> 6;           // wave id 0..3
    int ln = threadIdx.x & 63;           // lane
    int v = blockIdx.x * 4 + wv;
    if (v >= n) return;
    float dv = dinv[v];
    const float2* f2 = (const float2*)f1;   // row = 64 float2
    float2 self = f2[(size_t)v * 64 + ln];
    float sl = dv * dv;
    float ax = sl * self.x, ay = sl * self.y;
    float bx = 0.f, by = 0.f, cx = 0.f, cy = 0.f, dx = 0.f, dy = 0.f;
    int e0 = off[v], e1 = off[v + 1];
    int e = e0;
    for (; e + 4 <= e1; e += 4) {
        int s0 = src_sorted[e],     s1 = src_sorted[e + 1];
        int s2 = src_sorted[e + 2], s3 = src_sorted[e + 3];
        float n0 = dinv[s0] * dv, n1 = dinv[s1] * dv;
        float n2 = dinv[s2] * dv, n3 = dinv[s3] * dv;
        float2 r0 = f2[(size_t)s0 * 64 + ln];
        float2 r1 = f2[(size_t)s1 * 64 + ln];
        float2 r2 = f2[(size_t)s2 * 64 + ln];
        float2 r3 = f2[(size_t)s3 * 64 + ln];
        ax = fmaf(n0, r0.x, ax); ay = fmaf(n0, r0.y, ay);
        bx = fmaf(n1, r1.x, bx); by = fmaf(n1, r1.y, by);
        cx = fmaf(n2, r2.x, cx); cy = fmaf(n2, r2.y, cy);
        dx = fmaf(n3, r3.x, dx); dy = fmaf(n3, r3.y, dy);
    }
    for (; e < e1; e++) {
        int s = src_sorted[e];
        float nm = dinv[s] * dv;
        float2 r = f2[(size_t)s * 64 + ln];
        ax = fmaf(nm, r.x, ax); ay = fmaf(nm, r.y, ay);
    }
    float2 o;
    o.x = (ax + bx) + (cx + dx);
    o.y = (ay + by) + (cy + dy);
    ((float2*)acc2)[(size_t)v * 64 + ln] = o;
}

// K9: wave-GEMV GEMM + fused bias/ReLU/segment-pool.
// 1 wave per 64 nodes. lane = node. W2 rows come through the SCALAR path
// (uniform k,j indices -> s_load; SGPR operand in v_fmac). A staged once into
// LDS transposed [k][node] (stride 65, conflict-free). Inner loop:
// 1 prefetched ds_read_b32 + 64 FMAs per k per channel-half -> VALU-bound.
__global__ __launch_bounds__(64) void k_mm2_pool(
        const float* __restrict__ acc2, const float* __restrict__ W2,
        const float* __restrict__ b2, const int* __restrict__ batch,
        float* out, int n) {
    __shared__ float AsT[HID * 65];   // [k][node], stride 65
    __shared__ int bch[64];

    int t = threadIdx.x;              // 0..63, lane = node index in tile
    int v0 = blockIdx.x * 64;
    size_t gbase = (size_t)v0 * HID;
    size_t gmax = (size_t)n * HID;

    // stage + transpose: 128 rounds of 64 consecutive floats (coalesced).
    // local idx L = j*64+t -> node = j>>1, k = (j&1)*64+t. ds_write stride 65
    // -> bank delta 1 -> conflict-free.
    for (int j = 0; j < 2 * 64; j++) {
        size_t gi = gbase + (size_t)j * 64 + t;
        float val = (gi < gmax) ? acc2[gi] : 0.0f;
        int node = j >> 1;
        int k = ((j & 1) << 6) + t;
        AsT[k * 65 + node] = val;
    }
    {
        int v = v0 + t;
        bch[t] = (v < n) ? batch[v] : -1;
    }
    __syncthreads();

    // pass A: output channels 0..63
    float accA[64];
#pragma unroll
    for (int j = 0; j < 64; j++) accA[j] = 0.0f;
    {
        float a = AsT[t];                       // k=0, node=t
        for (int k = 0; k < HID; k++) {
            float a_next = (k + 1 < HID) ? AsT[(k + 1) * 65 + t] : 0.0f;
            const float* wr = W2 + k * HID;     // uniform -> s_load
#pragma unroll
            for (int j = 0; j < 64; j++)
                accA[j] = fmaf(a, wr[j], accA[j]);
            a = a_next;
        }
    }
    // pass B: output channels 64..127
    float accB[64];
#pragma unroll
    for (int j = 0; j < 64; j++) accB[j] = 0.0f;
    {
        float a = AsT[t];
        for (int k = 0; k < HID; k++) {
            float a_next = (k + 1 < HID) ? AsT[(k + 1) * 65 + t] : 0.0f;
            const float* wr = W2 + k * HID + 64;
#pragma unroll
            for (int j = 0; j < 64; j++)
                accB[j] = fmaf(a, wr[j], accB[j]);
            a = a_next;
        }
    }

    // bias + relu, write back transposed to LDS as [channel][node] stride 65
    __syncthreads();   // everyone done reading AsT before overwrite
#pragma unroll
    for (int j = 0; j < 64; j++) {
        float fa = accA[j] + b2[j];
        AsT[j * 65 + t] = fa > 0.0f ? fa : 0.0f;
    }
#pragma unroll
    for (int j = 0; j < 64; j++) {
        float fb = accB[j] + b2[64 + j];
        AsT[(64 + j) * 65 + t] = fb > 0.0f ? fb : 0.0f;
    }
    __syncthreads();

    // pool: lane t owns channels t and t+64; run over 64 nodes (batch sorted)
    float run0 = 0.0f, run1 = 0.0f;
    int cur = bch[0];
    for (int v = 0; v < 64; v++) {
        int b = bch[v];
        if (b < 0) break;               // invalid suffix
        if (b != cur) {
            atomicAdd(&out[cur * HID + t], run0);
            atomicAdd(&out[cur * HID + 64 + t], run1);
            run0 = 0.0f; run1 = 0.0f;
            cur = b;
        }
        run0 += AsT[t * 65 + v];
        run1 += AsT[(64 + t) * 65 + v];
    }
    if (cur >= 0) {
        atomicAdd(&out[cur * HID + t], run0);
        atomicAdd(&out[cur * HID + 64 + t], run1);
    }
}

// K10: out[b][c] /= max(cnt[b], 1)
__global__ void k_div(float* out, const int* __restrict__ cnt, int outsz) {
    int i = blockIdx.x * blockDim.x + threadIdx.x;
    if (i < outsz) {
        int b = i >> 7;
        float cf = (float)cnt[b];
        out[i] = out[i] / fmaxf(cf, 1.0f);
    }
}

extern "C" void kernel_launch(void* const* d_in, const int* in_sizes, int n_in,
                              void* d_out, int out_size, void* d_ws, size_t ws_size,
                              hipStream_t stream) {
    const float* x   = (const float*)d_in[0];
    const int* ei    = (const int*)d_in[1];   // [2, E] flat: src then dst
    const int* batch = (const int*)d_in[2];
    const float* W1  = (const float*)d_in[3];
    const float* b1  = (const float*)d_in[4];
    const float* W2  = (const float*)d_in[5];
    const float* b2  = (const float*)d_in[6];
    float* out = (float*)d_out;

    int n  = in_sizes[0] / IN_C;
    int e  = in_sizes[1] / 2;
    int bg = out_size / HID;
    const int* src = ei;
    const int* dst = ei + e;

    size_t off_b = 0;
    char* base = (char*)d_ws;
    auto carve = [&](size_t bytes) -> void* {
        void* p = base + off_b;
        off_b += (bytes + 255) & ~(size_t)255;
        return p;
    };
    int nbScan = (n + SCAN_CHUNK - 1) / SCAN_CHUNK;
    int*   deg_i      = (int*)carve((size_t)n * 4);
    int*   off        = (int*)carve((size_t)(n + 1) * 4);
    int*   cursor     = (int*)carve((size_t)n * 4);
    int*   src_sorted = (int*)carve((size_t)e * 4);
    float* dinv       = (float*)carve((size_t)n * 4);
    int*   bsum       = (int*)carve((size_t)nbScan * 4);
    float* xp         = (float*)carve((size_t)n * IN_C * 4);
    float* f1         = (float*)carve((size_t)n * HID * 4);
    float* acc2       = (float*)carve((size_t)n * HID * 4);
    int*   cnt        = (int*)carve((size_t)bg * 4);
    (void)ws_size;

    int gN = (n + TPB - 1) / TPB;
    int gE = (e + TPB - 1) / TPB;

    k_init<<<gN, TPB, 0, stream>>>(deg_i, out, n, out_size);
    k_hist<<<gE, TPB, 0, stream>>>(dst, deg_i, e);
    k_cnt<<<1, 64, 0, stream>>>(batch, cnt, n, bg);
    k_scan_part<<<nbScan, SCAN_TPB, 0, stream>>>(deg_i, bsum, n);
    k_scan_bsum<<<1, 1024, 0, stream>>>(bsum, nbScan);
    k_scan_final<<<nbScan, SCAN_TPB, 0, stream>>>(deg_i, bsum, off, cursor, dinv, n, e);
    k_fillpos<<<gE, TPB, 0, stream>>>(src, dst, cursor, src_sorted, e);
    k_gather1<<<gN, TPB, 0, stream>>>(off, src_sorted, dinv, x, xp, n);
    k_f1<<<(n * HID + TPB - 1) / TPB, TPB, 0, stream>>>(xp, W1, b1, f1, n);
    k_gather2<<<(n + 3) / 4, 256, 0, stream>>>(off, src_sorted, dinv, f1, acc2, n);
    k_mm2_pool<<<(n + 63) / 64, 64, 0, stream>>>(acc2, W2, b2, batch, out, n);
    k_div<<<(out_size + TPB - 1) / TPB, TPB, 0, stream>>>(out, cnt, out_size);
}

// Round 7
// 563.128 us; speedup vs baseline: 1.3714x; 1.3714x over previous
//
#include <hip/hip_runtime.h>

#define TPB 256
#define HID 128
#define IN_C 4
#define SCAN_TPB 256
#define SCAN_CHUNK 1024   // 4 elements per thread
#define GEMM_TPB 256
#define TILE_N 64

// ---------------------------------------------------------------------------
// K0: zero deg_i and out
__global__ void k_init(int* deg_i, float* out, int n, int outsz) {
    int i = blockIdx.x * blockDim.x + threadIdx.x;
    if (i < n) deg_i[i] = 0;
    if (i < outsz) out[i] = 0.0f;
}

// K1: in-degree histogram (int atomics, random dsts -> low contention)
__global__ void k_hist(const int* __restrict__ dst, int* deg_i, int e) {
    int i = blockIdx.x * blockDim.x + threadIdx.x;
    if (i < e) atomicAdd(&deg_i[dst[i]], 1);
}

// K2: per-graph node counts via binary search on sorted batch (no atomics)
__global__ void k_cnt(const int* __restrict__ batch, int* cnt, int n, int bg) {
    int b = blockIdx.x * blockDim.x + threadIdx.x;
    if (b >= bg) return;
    int lo0 = 0, hi0 = n;
    while (lo0 < hi0) { int m = (lo0 + hi0) >> 1; if (batch[m] < b) lo0 = m + 1; else hi0 = m; }
    int lo1 = lo0, hi1 = n;
    while (lo1 < hi1) { int m = (lo1 + hi1) >> 1; if (batch[m] < b + 1) lo1 = m + 1; else hi1 = m; }
    cnt[b] = lo1 - lo0;
}

// K3a: per-block sums of deg_i (block = SCAN_CHUNK elements)
__global__ __launch_bounds__(SCAN_TPB) void k_scan_part(const int* __restrict__ deg_i,
                                                        int* bsum, int n) {
    __shared__ int red[SCAN_TPB];
    int b = blockIdx.x, t = threadIdx.x;
    int base = b * SCAN_CHUNK + t * 4;
    int s = 0;
#pragma unroll
    for (int k = 0; k < 4; k++) {
        int i = base + k;
        if (i < n) s += deg_i[i];
    }
    red[t] = s;
    __syncthreads();
    for (int d = SCAN_TPB / 2; d > 0; d >>= 1) {
        if (t < d) red[t] += red[t + d];
        __syncthreads();
    }
    if (t == 0) bsum[b] = red[0];
}

// K3b: single-block exclusive scan of block sums
__global__ __launch_bounds__(1024) void k_scan_bsum(int* bsum, int nb) {
    __shared__ int red[1024];
    int t = threadIdx.x;
    int carry = 0;
    for (int base = 0; base < nb; base += 1024) {
        int i = base + t;
        int v = (i < nb) ? bsum[i] : 0;
        red[t] = v;
        __syncthreads();
        for (int d = 1; d < 1024; d <<= 1) {
            int x = 0;
            if (t >= d) x = red[t - d];
            __syncthreads();
            if (t >= d) red[t] += x;
            __syncthreads();
        }
        int tot = red[1023];
        if (i < nb) bsum[i] = carry + red[t] - v;   // exclusive
        carry += tot;
        __syncthreads();
    }
}

// K3c: final scan pass -> off, cursor; fused dinv = rsqrt(deg+1)
__global__ __launch_bounds__(SCAN_TPB) void k_scan_final(
        const int* __restrict__ deg_i, const int* __restrict__ bsum,
        int* off, int* cursor, float* dinv, int n, int e) {
    __shared__ int red[SCAN_TPB];
    int b = blockIdx.x, t = threadIdx.x;
    int base = b * SCAN_CHUNK + t * 4;
    int v[4];
    int s = 0;
#pragma unroll
    for (int k = 0; k < 4; k++) {
        int i = base + k;
        v[k] = (i < n) ? deg_i[i] : 0;
        s += v[k];
    }
    red[t] = s;
    __syncthreads();
    for (int d = 1; d < SCAN_TPB; d <<= 1) {
        int x = 0;
        if (t >= d) x = red[t - d];
        __syncthreads();
        if (t >= d) red[t] += x;
        __syncthreads();
    }
    int run = bsum[b] + red[t] - s;
#pragma unroll
    for (int k = 0; k < 4; k++) {
        int i = base + k;
        if (i < n) {
            off[i] = run;
            cursor[i] = run;
            dinv[i] = rsqrtf((float)v[k] + 1.0f);
            run += v[k];
        }
    }
    if (b == 0 && t == 0) off[n] = e;
}

// K5: counting-sort fill: src_sorted grouped by dst
__global__ void k_fillpos(const int* __restrict__ src, const int* __restrict__ dst,
                          int* cursor, int* src_sorted, int e) {
    int i = blockIdx.x * blockDim.x + threadIdx.x;
    if (i >= e) return;
    int d = dst[i];
    int p = atomicAdd(&cursor[d], 1);
    src_sorted[p] = src[i];
}

// K6: layer-1 propagation as gather on raw 4-channel x; unroll x4 for MLP
__global__ void k_gather1(const int* __restrict__ off, const int* __restrict__ src_sorted,
                          const float* __restrict__ dinv, const float* __restrict__ x,
                          float* xp, int n) {
    int v = blockIdx.x * blockDim.x + threadIdx.x;
    if (v >= n) return;
    float dv = dinv[v];
    const float4* x4 = (const float4*)x;
    float4 xv = x4[v];
    float sl = dv * dv;
    float4 A = make_float4(sl * xv.x, sl * xv.y, sl * xv.z, sl * xv.w);
    float4 B = make_float4(0.f, 0.f, 0.f, 0.f);
    float4 C = make_float4(0.f, 0.f, 0.f, 0.f);
    float4 D = make_float4(0.f, 0.f, 0.f, 0.f);
    int e0 = off[v], e1 = off[v + 1];
    int e = e0;
    for (; e + 4 <= e1; e += 4) {
        int s0 = src_sorted[e], s1 = src_sorted[e + 1];
        int s2 = src_sorted[e + 2], s3 = src_sorted[e + 3];
        float n0 = dinv[s0] * dv, n1 = dinv[s1] * dv;
        float n2 = dinv[s2] * dv, n3 = dinv[s3] * dv;
        float4 r0 = x4[s0], r1 = x4[s1], r2 = x4[s2], r3 = x4[s3];
        A.x = fmaf(n0, r0.x, A.x); A.y = fmaf(n0, r0.y, A.y);
        A.z = fmaf(n0, r0.z, A.z); A.w = fmaf(n0, r0.w, A.w);
        B.x = fmaf(n1, r1.x, B.x); B.y = fmaf(n1, r1.y, B.y);
        B.z = fmaf(n1, r1.z, B.z); B.w = fmaf(n1, r1.w, B.w);
        C.x = fmaf(n2, r2.x, C.x); C.y = fmaf(n2, r2.y, C.y);
        C.z = fmaf(n2, r2.z, C.z); C.w = fmaf(n2, r2.w, C.w);
        D.x = fmaf(n3, r3.x, D.x); D.y = fmaf(n3, r3.y, D.y);
        D.z = fmaf(n3, r3.z, D.z); D.w = fmaf(n3, r3.w, D.w);
    }
    for (; e < e1; e++) {
        int s = src_sorted[e];
        float nm = dinv[s] * dv;
        float4 r = x4[s];
        A.x = fmaf(nm, r.x, A.x); A.y = fmaf(nm, r.y, A.y);
        A.z = fmaf(nm, r.z, A.z); A.w = fmaf(nm, r.w, A.w);
    }
    float4 o;
    o.x = (A.x + B.x) + (C.x + D.x);
    o.y = (A.y + B.y) + (C.y + D.y);
    o.z = (A.z + B.z) + (C.z + D.z);
    o.w = (A.w + B.w) + (C.w + D.w);
    ((float4*)xp)[v] = o;
}

// K7: f1 = relu(xp @ W1 + b1)
__global__ void k_f1(const float* __restrict__ xp, const float* __restrict__ W1,
                     const float* __restrict__ b1, float* f1, int n) {
    int i = blockIdx.x * blockDim.x + threadIdx.x;
    if (i >= n * HID) return;
    int v = i >> 7, c = i & (HID - 1);
    const float4* xr = (const float4*)(xp + v * IN_C);
    float4 xv = *xr;
    float s = fmaf(xv.x, W1[c],
              fmaf(xv.y, W1[HID + c],
              fmaf(xv.z, W1[2 * HID + c],
              fmaf(xv.w, W1[3 * HID + c], b1[c]))));
    f1[i] = s > 0.0f ? s : 0.0f;
}

// K8: layer-2 gather: one WAVE per node, float2 per lane, x4 unrolled MLP
__global__ __launch_bounds__(256) void k_gather2(
        const int* __restrict__ off, const int* __restrict__ src_sorted,
        const float* __restrict__ dinv, const float* __restrict__ f1,
        float* acc2, int n) {
    int wv = threadIdx.x >> 6;           // wave id 0..3
    int ln = threadIdx.x & 63;           // lane
    int v = blockIdx.x * 4 + wv;
    if (v >= n) return;
    float dv = dinv[v];
    const float2* f2 = (const float2*)f1;   // row = 64 float2
    float2 self = f2[(size_t)v * 64 + ln];
    float sl = dv * dv;
    float ax = sl * self.x, ay = sl * self.y;
    float bx = 0.f, by = 0.f, cx = 0.f, cy = 0.f, dx = 0.f, dy = 0.f;
    int e0 = off[v], e1 = off[v + 1];
    int e = e0;
    for (; e + 4 <= e1; e += 4) {
        int s0 = src_sorted[e],     s1 = src_sorted[e + 1];
        int s2 = src_sorted[e + 2], s3 = src_sorted[e + 3];
        float n0 = dinv[s0] * dv, n1 = dinv[s1] * dv;
        float n2 = dinv[s2] * dv, n3 = dinv[s3] * dv;
        float2 r0 = f2[(size_t)s0 * 64 + ln];
        float2 r1 = f2[(size_t)s1 * 64 + ln];
        float2 r2 = f2[(size_t)s2 * 64 + ln];
        float2 r3 = f2[(size_t)s3 * 64 + ln];
        ax = fmaf(n0, r0.x, ax); ay = fmaf(n0, r0.y, ay);
        bx = fmaf(n1, r1.x, bx); by = fmaf(n1, r1.y, by);
        cx = fmaf(n2, r2.x, cx); cy = fmaf(n2, r2.y, cy);
        dx = fmaf(n3, r3.x, dx); dy = fmaf(n3, r3.y, dy);
    }
    for (; e < e1; e++) {
        int s = src_sorted[e];
        float nm = dinv[s] * dv;
        float2 r = f2[(size_t)s * 64 + ln];
        ax = fmaf(nm, r.x, ax); ay = fmaf(nm, r.y, ay);
    }
    float2 o;
    o.x = (ax + bx) + (cx + dx);
    o.y = (ay + by) + (cy + dy);
    ((float2*)acc2)[(size_t)v * 64 + ln] = o;
}

// K9: tiled GEMM + fused bias/ReLU/segment-pool.
// A-tile (64 nodes x 128 ch) staged in LDS (33.8 KB); W2 read directly from
// global (64 KB, L2-resident, lane-coalesced 512B rows) -> 4 blocks/CU,
// 16 waves/CU, single barrier. Each thread: 8 nodes x 4 channels.
__global__ __launch_bounds__(GEMM_TPB, 4) void k_mm2_pool(
        const float* __restrict__ acc2, const float* __restrict__ W2,
        const float* __restrict__ b2, const int* __restrict__ batch,
        float* out, int n) {
    __shared__ float As[TILE_N][132];   // node-major, pad 128->132 words
    __shared__ int bch[TILE_N];

    int t = threadIdx.x;
    int v0 = blockIdx.x * TILE_N;
    int cg = t & 31;          // channel quad: channels 4cg..4cg+3
    int ng = t >> 5;          // node octet: nodes 8ng..8ng+7
    int nd0 = ng * 8;

    // stage A tile: coalesced float4 row copy
#pragma unroll
    for (int j = 0; j < 8; j++) {
        int fi = t + GEMM_TPB * j;          // 0..2047
        int nd = fi >> 5, kq = fi & 31;
        int v = v0 + nd;
        if (v < n) {
            float4 a = ((const float4*)acc2)[(size_t)v * 32 + kq];
            *(float4*)&As[nd][kq * 4] = a;
        }
    }
    if (t < TILE_N) {
        int v = v0 + t;
        bch[t] = (v < n) ? batch[v] : -1;
    }
    __syncthreads();

    float4 acc[8];
#pragma unroll
    for (int i = 0; i < 8; i++) acc[i] = make_float4(0.f, 0.f, 0.f, 0.f);

    const float4* W2v = (const float4*)W2;   // row k = 32 float4
#pragma unroll 4
    for (int k4 = 0; k4 < 32; k4++) {
        int k0 = k4 * 4;
        float4 w0 = W2v[(k0 + 0) * 32 + cg];
        float4 w1 = W2v[(k0 + 1) * 32 + cg];
        float4 w2 = W2v[(k0 + 2) * 32 + cg];
        float4 w3 = W2v[(k0 + 3) * 32 + cg];
#pragma unroll
        for (int i = 0; i < 8; i++) {
            float4 a = *(float4*)&As[nd0 + i][k0];
            acc[i].x = fmaf(a.x, w0.x, acc[i].x);
            acc[i].y = fmaf(a.x, w0.y, acc[i].y);
            acc[i].z = fmaf(a.x, w0.z, acc[i].z);
            acc[i].w = fmaf(a.x, w0.w, acc[i].w);
            acc[i].x = fmaf(a.y, w1.x, acc[i].x);
            acc[i].y = fmaf(a.y, w1.y, acc[i].y);
            acc[i].z = fmaf(a.y, w1.z, acc[i].z);
            acc[i].w = fmaf(a.y, w1.w, acc[i].w);
            acc[i].x = fmaf(a.z, w2.x, acc[i].x);
            acc[i].y = fmaf(a.z, w2.y, acc[i].y);
            acc[i].z = fmaf(a.z, w2.z, acc[i].z);
            acc[i].w = fmaf(a.z, w2.w, acc[i].w);
            acc[i].x = fmaf(a.w, w3.x, acc[i].x);
            acc[i].y = fmaf(a.w, w3.y, acc[i].y);
            acc[i].z = fmaf(a.w, w3.z, acc[i].z);
            acc[i].w = fmaf(a.w, w3.w, acc[i].w);
        }
    }

    // epilogue: bias + relu + segment run-accumulate (batch sorted)
    float4 bb = *(const float4*)(b2 + cg * 4);
    int curb = -1;
    float4 run = make_float4(0.f, 0.f, 0.f, 0.f);
    for (int i = 0; i < 8; i++) {
        int b = bch[nd0 + i];
        if (b < 0) break;                    // invalid nodes are a suffix
        if (b != curb) {
            if (curb >= 0) {
                float* o = out + (size_t)curb * HID + cg * 4;
                atomicAdd(o + 0, run.x); atomicAdd(o + 1, run.y);
                atomicAdd(o + 2, run.z); atomicAdd(o + 3, run.w);
            }
            run = make_float4(0.f, 0.f, 0.f, 0.f);
            curb = b;
        }
        float fx = acc[i].x + bb.x; run.x += fx > 0.f ? fx : 0.f;
        float fy = acc[i].y + bb.y; run.y += fy > 0.f ? fy : 0.f;
        float fz = acc[i].z + bb.z; run.z += fz > 0.f ? fz : 0.f;
        float fw = acc[i].w + bb.w; run.w += fw > 0.f ? fw : 0.f;
    }
    if (curb >= 0) {
        float* o = out + (size_t)curb * HID + cg * 4;
        atomicAdd(o + 0, run.x); atomicAdd(o + 1, run.y);
        atomicAdd(o + 2, run.z); atomicAdd(o + 3, run.w);
    }
}

// K10: out[b][c] /= max(cnt[b], 1)
__global__ void k_div(float* out, const int* __restrict__ cnt, int outsz) {
    int i = blockIdx.x * blockDim.x + threadIdx.x;
    if (i < outsz) {
        int b = i >> 7;
        float cf = (float)cnt[b];
        out[i] = out[i] / fmaxf(cf, 1.0f);
    }
}

extern "C" void kernel_launch(void* const* d_in, const int* in_sizes, int n_in,
                              void* d_out, int out_size, void* d_ws, size_t ws_size,
                              hipStream_t stream) {
    const float* x   = (const float*)d_in[0];
    const int* ei    = (const int*)d_in[1];   // [2, E] flat: src then dst
    const int* batch = (const int*)d_in[2];
    const float* W1  = (const float*)d_in[3];
    const float* b1  = (const float*)d_in[4];
    const float* W2  = (const float*)d_in[5];
    const float* b2  = (const float*)d_in[6];
    float* out = (float*)d_out;

    int n  = in_sizes[0] / IN_C;
    int e  = in_sizes[1] / 2;
    int bg = out_size / HID;
    const int* src = ei;
    const int* dst = ei + e;

    size_t off_b = 0;
    char* base = (char*)d_ws;
    auto carve = [&](size_t bytes) -> void* {
        void* p = base + off_b;
        off_b += (bytes + 255) & ~(size_t)255;
        return p;
    };
    int nbScan = (n + SCAN_CHUNK - 1) / SCAN_CHUNK;
    int*   deg_i      = (int*)carve((size_t)n * 4);
    int*   off        = (int*)carve((size_t)(n + 1) * 4);
    int*   cursor     = (int*)carve((size_t)n * 4);
    int*   src_sorted = (int*)carve((size_t)e * 4);
    float* dinv       = (float*)carve((size_t)n * 4);
    int*   bsum       = (int*)carve((size_t)nbScan * 4);
    float* xp         = (float*)carve((size_t)n * IN_C * 4);
    float* f1         = (float*)carve((size_t)n * HID * 4);
    float* acc2       = (float*)carve((size_t)n * HID * 4);
    int*   cnt        = (int*)carve((size_t)bg * 4);
    (void)ws_size;

    int gN = (n + TPB - 1) / TPB;
    int gE = (e + TPB - 1) / TPB;

    k_init<<<gN, TPB, 0, stream>>>(deg_i, out, n, out_size);
    k_hist<<<gE, TPB, 0, stream>>>(dst, deg_i, e);
    k_cnt<<<1, 64, 0, stream>>>(batch, cnt, n, bg);
    k_scan_part<<<nbScan, SCAN_TPB, 0, stream>>>(deg_i, bsum, n);
    k_scan_bsum<<<1, 1024, 0, stream>>>(bsum, nbScan);
    k_scan_final<<<nbScan, SCAN_TPB, 0, stream>>>(deg_i, bsum, off, cursor, dinv, n, e);
    k_fillpos<<<gE, TPB, 0, stream>>>(src, dst, cursor, src_sorted, e);
    k_gather1<<<gN, TPB, 0, stream>>>(off, src_sorted, dinv, x, xp, n);
    k_f1<<<(n * HID + TPB - 1) / TPB, TPB, 0, stream>>>(xp, W1, b1, f1, n);
    k_gather2<<<(n + 3) / 4, 256, 0, stream>>>(off, src_sorted, dinv, f1, acc2, n);
    k_mm2_pool<<<(n + TILE_N - 1) / TILE_N, GEMM_TPB, 0, stream>>>(acc2, W2, b2, batch, out, n);
    k_div<<<(out_size + TPB - 1) / TPB, TPB, 0, stream>>>(out, cnt, out_size);
}

// Round 8
// 549.542 us; speedup vs baseline: 1.4053x; 1.0247x over previous
//
#include <hip/hip_runtime.h>

#define TPB 256
#define HID 128
#define IN_C 4
#define SCAN_TPB 256
#define SCAN_CHUNK 1024   // 4 elements per thread
#define GEMM_TPB 256
#define TILE_N 64

// ---------------------------------------------------------------------------
// K0: zero deg_i and out
__global__ void k_init(int* deg_i, float* out, int n, int outsz) {
    int i = blockIdx.x * blockDim.x + threadIdx.x;
    if (i < n) deg_i[i] = 0;
    if (i < outsz) out[i] = 0.0f;
}

// K1: in-degree histogram (int atomics, random dsts -> low contention)
__global__ void k_hist(const int* __restrict__ dst, int* deg_i, int e) {
    int i = blockIdx.x * blockDim.x + threadIdx.x;
    if (i < e) atomicAdd(&deg_i[dst[i]], 1);
}

// K2: per-graph node counts via binary search on sorted batch (no atomics)
__global__ void k_cnt(const int* __restrict__ batch, int* cnt, int n, int bg) {
    int b = blockIdx.x * blockDim.x + threadIdx.x;
    if (b >= bg) return;
    int lo0 = 0, hi0 = n;
    while (lo0 < hi0) { int m = (lo0 + hi0) >> 1; if (batch[m] < b) lo0 = m + 1; else hi0 = m; }
    int lo1 = lo0, hi1 = n;
    while (lo1 < hi1) { int m = (lo1 + hi1) >> 1; if (batch[m] < b + 1) lo1 = m + 1; else hi1 = m; }
    cnt[b] = lo1 - lo0;
}

// K3a: per-block sums of deg_i (block = SCAN_CHUNK elements)
__global__ __launch_bounds__(SCAN_TPB) void k_scan_part(const int* __restrict__ deg_i,
                                                        int* bsum, int n) {
    __shared__ int red[SCAN_TPB];
    int b = blockIdx.x, t = threadIdx.x;
    int base = b * SCAN_CHUNK + t * 4;
    int s = 0;
#pragma unroll
    for (int k = 0; k < 4; k++) {
        int i = base + k;
        if (i < n) s += deg_i[i];
    }
    red[t] = s;
    __syncthreads();
    for (int d = SCAN_TPB / 2; d > 0; d >>= 1) {
        if (t < d) red[t] += red[t + d];
        __syncthreads();
    }
    if (t == 0) bsum[b] = red[0];
}

// K3b: single-block exclusive scan of block sums
__global__ __launch_bounds__(1024) void k_scan_bsum(int* bsum, int nb) {
    __shared__ int red[1024];
    int t = threadIdx.x;
    int carry = 0;
    for (int base = 0; base < nb; base += 1024) {
        int i = base + t;
        int v = (i < nb) ? bsum[i] : 0;
        red[t] = v;
        __syncthreads();
        for (int d = 1; d < 1024; d <<= 1) {
            int x = 0;
            if (t >= d) x = red[t - d];
            __syncthreads();
            if (t >= d) red[t] += x;
            __syncthreads();
        }
        int tot = red[1023];
        if (i < nb) bsum[i] = carry + red[t] - v;   // exclusive
        carry += tot;
        __syncthreads();
    }
}

// K3c: final scan pass -> off, cursor; fused dinv = rsqrt(deg+1)
__global__ __launch_bounds__(SCAN_TPB) void k_scan_final(
        const int* __restrict__ deg_i, const int* __restrict__ bsum,
        int* off, int* cursor, float* dinv, int n, int e) {
    __shared__ int red[SCAN_TPB];
    int b = blockIdx.x, t = threadIdx.x;
    int base = b * SCAN_CHUNK + t * 4;
    int v[4];
    int s = 0;
#pragma unroll
    for (int k = 0; k < 4; k++) {
        int i = base + k;
        v[k] = (i < n) ? deg_i[i] : 0;
        s += v[k];
    }
    red[t] = s;
    __syncthreads();
    for (int d = 1; d < SCAN_TPB; d <<= 1) {
        int x = 0;
        if (t >= d) x = red[t - d];
        __syncthreads();
        if (t >= d) red[t] += x;
        __syncthreads();
    }
    int run = bsum[b] + red[t] - s;
#pragma unroll
    for (int k = 0; k < 4; k++) {
        int i = base + k;
        if (i < n) {
            off[i] = run;
            cursor[i] = run;
            dinv[i] = rsqrtf((float)v[k] + 1.0f);
            run += v[k];
        }
    }
    if (b == 0 && t == 0) off[n] = e;
}

// K5: counting-sort fill: src_sorted grouped by dst
__global__ void k_fillpos(const int* __restrict__ src, const int* __restrict__ dst,
                          int* cursor, int* src_sorted, int e) {
    int i = blockIdx.x * blockDim.x + threadIdx.x;
    if (i >= e) return;
    int d = dst[i];
    int p = atomicAdd(&cursor[d], 1);
    src_sorted[p] = src[i];
}

// K6: layer-1 propagation as gather on raw 4-channel x; unroll x4 for MLP
__global__ void k_gather1(const int* __restrict__ off, const int* __restrict__ src_sorted,
                          const float* __restrict__ dinv, const float* __restrict__ x,
                          float* xp, int n) {
    int v = blockIdx.x * blockDim.x + threadIdx.x;
    if (v >= n) return;
    float dv = dinv[v];
    const float4* x4 = (const float4*)x;
    float4 xv = x4[v];
    float sl = dv * dv;
    float4 A = make_float4(sl * xv.x, sl * xv.y, sl * xv.z, sl * xv.w);
    float4 B = make_float4(0.f, 0.f, 0.f, 0.f);
    float4 C = make_float4(0.f, 0.f, 0.f, 0.f);
    float4 D = make_float4(0.f, 0.f, 0.f, 0.f);
    int e0 = off[v], e1 = off[v + 1];
    int e = e0;
    for (; e + 4 <= e1; e += 4) {
        int s0 = src_sorted[e], s1 = src_sorted[e + 1];
        int s2 = src_sorted[e + 2], s3 = src_sorted[e + 3];
        float n0 = dinv[s0] * dv, n1 = dinv[s1] * dv;
        float n2 = dinv[s2] * dv, n3 = dinv[s3] * dv;
        float4 r0 = x4[s0], r1 = x4[s1], r2 = x4[s2], r3 = x4[s3];
        A.x = fmaf(n0, r0.x, A.x); A.y = fmaf(n0, r0.y, A.y);
        A.z = fmaf(n0, r0.z, A.z); A.w = fmaf(n0, r0.w, A.w);
        B.x = fmaf(n1, r1.x, B.x); B.y = fmaf(n1, r1.y, B.y);
        B.z = fmaf(n1, r1.z, B.z); B.w = fmaf(n1, r1.w, B.w);
        C.x = fmaf(n2, r2.x, C.x); C.y = fmaf(n2, r2.y, C.y);
        C.z = fmaf(n2, r2.z, C.z); C.w = fmaf(n2, r2.w, C.w);
        D.x = fmaf(n3, r3.x, D.x); D.y = fmaf(n3, r3.y, D.y);
        D.z = fmaf(n3, r3.z, D.z); D.w = fmaf(n3, r3.w, D.w);
    }
    for (; e < e1; e++) {
        int s = src_sorted[e];
        float nm = dinv[s] * dv;
        float4 r = x4[s];
        A.x = fmaf(nm, r.x, A.x); A.y = fmaf(nm, r.y, A.y);
        A.z = fmaf(nm, r.z, A.z); A.w = fmaf(nm, r.w, A.w);
    }
    float4 o;
    o.x = (A.x + B.x) + (C.x + D.x);
    o.y = (A.y + B.y) + (C.y + D.y);
    o.z = (A.z + B.z) + (C.z + D.z);
    o.w = (A.w + B.w) + (C.w + D.w);
    ((float4*)xp)[v] = o;
}

// K7: f1 = relu(xp @ W1 + b1)
__global__ void k_f1(const float* __restrict__ xp, const float* __restrict__ W1,
                     const float* __restrict__ b1, float* f1, int n) {
    int i = blockIdx.x * blockDim.x + threadIdx.x;
    if (i >= n * HID) return;
    int v = i >> 7, c = i & (HID - 1);
    const float4* xr = (const float4*)(xp + v * IN_C);
    float4 xv = *xr;
    float s = fmaf(xv.x, W1[c],
              fmaf(xv.y, W1[HID + c],
              fmaf(xv.z, W1[2 * HID + c],
              fmaf(xv.w, W1[3 * HID + c], b1[c]))));
    f1[i] = s > 0.0f ? s : 0.0f;
}

// K8: layer-2 gather: one WAVE per node, float2 per lane, x4 unrolled MLP
__global__ __launch_bounds__(256) void k_gather2(
        const int* __restrict__ off, const int* __restrict__ src_sorted,
        const float* __restrict__ dinv, const float* __restrict__ f1,
        float* acc2, int n) {
    int wv = threadIdx.x >> 6;           // wave id 0..3
    int ln = threadIdx.x & 63;           // lane
    int v = blockIdx.x * 4 + wv;
    if (v >= n) return;
    float dv = dinv[v];
    const float2* f2 = (const float2*)f1;   // row = 64 float2
    float2 self = f2[(size_t)v * 64 + ln];
    float sl = dv * dv;
    float ax = sl * self.x, ay = sl * self.y;
    float bx = 0.f, by = 0.f, cx = 0.f, cy = 0.f, dx = 0.f, dy = 0.f;
    int e0 = off[v], e1 = off[v + 1];
    int e = e0;
    for (; e + 4 <= e1; e += 4) {
        int s0 = src_sorted[e],     s1 = src_sorted[e + 1];
        int s2 = src_sorted[e + 2], s3 = src_sorted[e + 3];
        float n0 = dinv[s0] * dv, n1 = dinv[s1] * dv;
        float n2 = dinv[s2] * dv, n3 = dinv[s3] * dv;
        float2 r0 = f2[(size_t)s0 * 64 + ln];
        float2 r1 = f2[(size_t)s1 * 64 + ln];
        float2 r2 = f2[(size_t)s2 * 64 + ln];
        float2 r3 = f2[(size_t)s3 * 64 + ln];
        ax = fmaf(n0, r0.x, ax); ay = fmaf(n0, r0.y, ay);
        bx = fmaf(n1, r1.x, bx); by = fmaf(n1, r1.y, by);
        cx = fmaf(n2, r2.x, cx); cy = fmaf(n2, r2.y, cy);
        dx = fmaf(n3, r3.x, dx); dy = fmaf(n3, r3.y, dy);
    }
    for (; e < e1; e++) {
        int s = src_sorted[e];
        float nm = dinv[s] * dv;
        float2 r = f2[(size_t)s * 64 + ln];
        ax = fmaf(nm, r.x, ax); ay = fmaf(nm, r.y, ay);
    }
    float2 o;
    o.x = (ax + bx) + (cx + dx);
    o.y = (ay + by) + (cy + dy);
    ((float2*)acc2)[(size_t)v * 64 + ln] = o;
}

// K9: tiled GEMM + fused bias/ReLU/segment-pool.
// A-tile in LDS (33.8 KB, 4 blocks/CU); W2 from global (L2-resident) with an
// EXPLICIT register double-buffer so next iteration's W loads are in flight
// under this iteration's 512 FMAs. A-reads batched (8 ds_read_b128) per iter.
__global__ __launch_bounds__(GEMM_TPB, 4) void k_mm2_pool(
        const float* __restrict__ acc2, const float* __restrict__ W2,
        const float* __restrict__ b2, const int* __restrict__ batch,
        float* out, int n) {
    __shared__ float As[TILE_N][132];   // node-major, pad 128->132 words
    __shared__ int bch[TILE_N];

    int t = threadIdx.x;
    int v0 = blockIdx.x * TILE_N;
    int cg = t & 31;          // channel quad: channels 4cg..4cg+3
    int ng = t >> 5;          // node octet: nodes 8ng..8ng+7
    int nd0 = ng * 8;

    // stage A tile: coalesced float4 row copy
#pragma unroll
    for (int j = 0; j < 8; j++) {
        int fi = t + GEMM_TPB * j;          // 0..2047
        int nd = fi >> 5, kq = fi & 31;
        int v = v0 + nd;
        if (v < n) {
            float4 a = ((const float4*)acc2)[(size_t)v * 32 + kq];
            *(float4*)&As[nd][kq * 4] = a;
        }
    }
    if (t < TILE_N) {
        int v = v0 + t;
        bch[t] = (v < n) ? batch[v] : -1;
    }
    __syncthreads();

    float4 acc[8];
#pragma unroll
    for (int i = 0; i < 8; i++) acc[i] = make_float4(0.f, 0.f, 0.f, 0.f);

    const float4* W2v = (const float4*)W2;   // row k = 32 float4

    float4 w[4];
#pragma unroll
    for (int j = 0; j < 4; j++) w[j] = W2v[j * 32 + cg];

    for (int k4 = 0; k4 < 32; k4++) {
        int k0 = k4 * 4;
        // prefetch next iteration's W (clamped index, unconditional)
        int kn = (k4 < 31) ? (k0 + 4) : 0;
        float4 wn[4];
#pragma unroll
        for (int j = 0; j < 4; j++) wn[j] = W2v[(kn + j) * 32 + cg];
        // batch the 8 LDS A-reads
        float4 a[8];
#pragma unroll
        for (int i = 0; i < 8; i++) a[i] = *(float4*)&As[nd0 + i][k0];
#pragma unroll
        for (int i = 0; i < 8; i++) {
            acc[i].x = fmaf(a[i].x, w[0].x, acc[i].x);
            acc[i].y = fmaf(a[i].x, w[0].y, acc[i].y);
            acc[i].z = fmaf(a[i].x, w[0].z, acc[i].z);
            acc[i].w = fmaf(a[i].x, w[0].w, acc[i].w);
            acc[i].x = fmaf(a[i].y, w[1].x, acc[i].x);
            acc[i].y = fmaf(a[i].y, w[1].y, acc[i].y);
            acc[i].z = fmaf(a[i].y, w[1].z, acc[i].z);
            acc[i].w = fmaf(a[i].y, w[1].w, acc[i].w);
            acc[i].x = fmaf(a[i].z, w[2].x, acc[i].x);
            acc[i].y = fmaf(a[i].z, w[2].y, acc[i].y);
            acc[i].z = fmaf(a[i].z, w[2].z, acc[i].z);
            acc[i].w = fmaf(a[i].z, w[2].w, acc[i].w);
            acc[i].x = fmaf(a[i].w, w[3].x, acc[i].x);
            acc[i].y = fmaf(a[i].w, w[3].y, acc[i].y);
            acc[i].z = fmaf(a[i].w, w[3].z, acc[i].z);
            acc[i].w = fmaf(a[i].w, w[3].w, acc[i].w);
        }
#pragma unroll
        for (int j = 0; j < 4; j++) w[j] = wn[j];
    }

    // epilogue: bias + relu + segment run-accumulate (batch sorted)
    float4 bb = *(const float4*)(b2 + cg * 4);
    int curb = -1;
    float4 run = make_float4(0.f, 0.f, 0.f, 0.f);
    for (int i = 0; i < 8; i++) {
        int b = bch[nd0 + i];
        if (b < 0) break;                    // invalid nodes are a suffix
        if (b != curb) {
            if (curb >= 0) {
                float* o = out + (size_t)curb * HID + cg * 4;
                atomicAdd(o + 0, run.x); atomicAdd(o + 1, run.y);
                atomicAdd(o + 2, run.z); atomicAdd(o + 3, run.w);
            }
            run = make_float4(0.f, 0.f, 0.f, 0.f);
            curb = b;
        }
        float fx = acc[i].x + bb.x; run.x += fx > 0.f ? fx : 0.f;
        float fy = acc[i].y + bb.y; run.y += fy > 0.f ? fy : 0.f;
        float fz = acc[i].z + bb.z; run.z += fz > 0.f ? fz : 0.f;
        float fw = acc[i].w + bb.w; run.w += fw > 0.f ? fw : 0.f;
    }
    if (curb >= 0) {
        float* o = out + (size_t)curb * HID + cg * 4;
        atomicAdd(o + 0, run.x); atomicAdd(o + 1, run.y);
        atomicAdd(o + 2, run.z); atomicAdd(o + 3, run.w);
    }
}

// K10: out[b][c] /= max(cnt[b], 1)
__global__ void k_div(float* out, const int* __restrict__ cnt, int outsz) {
    int i = blockIdx.x * blockDim.x + threadIdx.x;
    if (i < outsz) {
        int b = i >> 7;
        float cf = (float)cnt[b];
        out[i] = out[i] / fmaxf(cf, 1.0f);
    }
}

extern "C" void kernel_launch(void* const* d_in, const int* in_sizes, int n_in,
                              void* d_out, int out_size, void* d_ws, size_t ws_size,
                              hipStream_t stream) {
    const float* x   = (const float*)d_in[0];
    const int* ei    = (const int*)d_in[1];   // [2, E] flat: src then dst
    const int* batch = (const int*)d_in[2];
    const float* W1  = (const float*)d_in[3];
    const float* b1  = (const float*)d_in[4];
    const float* W2  = (const float*)d_in[5];
    const float* b2  = (const float*)d_in[6];
    float* out = (float*)d_out;

    int n  = in_sizes[0] / IN_C;
    int e  = in_sizes[1] / 2;
    int bg = out_size / HID;
    const int* src = ei;
    const int* dst = ei + e;

    size_t off_b = 0;
    char* base = (char*)d_ws;
    auto carve = [&](size_t bytes) -> void* {
        void* p = base + off_b;
        off_b += (bytes + 255) & ~(size_t)255;
        return p;
    };
    int nbScan = (n + SCAN_CHUNK - 1) / SCAN_CHUNK;
    int*   deg_i      = (int*)carve((size_t)n * 4);
    int*   off        = (int*)carve((size_t)(n + 1) * 4);
    int*   cursor     = (int*)carve((size_t)n * 4);
    int*   src_sorted = (int*)carve((size_t)e * 4);
    float* dinv       = (float*)carve((size_t)n * 4);
    int*   bsum       = (int*)carve((size_t)nbScan * 4);
    float* xp         = (float*)carve((size_t)n * IN_C * 4);
    float* f1         = (float*)carve((size_t)n * HID * 4);
    float* acc2       = (float*)carve((size_t)n * HID * 4);
    int*   cnt        = (int*)carve((size_t)bg * 4);
    (void)ws_size;

    int gN = (n + TPB - 1) / TPB;
    int gE = (e + TPB - 1) / TPB;

    k_init<<<gN, TPB, 0, stream>>>(deg_i, out, n, out_size);
    k_hist<<<gE, TPB, 0, stream>>>(dst, deg_i, e);
    k_cnt<<<1, 64, 0, stream>>>(batch, cnt, n, bg);
    k_scan_part<<<nbScan, SCAN_TPB, 0, stream>>>(deg_i, bsum, n);
    k_scan_bsum<<<1, 1024, 0, stream>>>(bsum, nbScan);
    k_scan_final<<<nbScan, SCAN_TPB, 0, stream>>>(deg_i, bsum, off, cursor, dinv, n, e);
    k_fillpos<<<gE, TPB, 0, stream>>>(src, dst, cursor, src_sorted, e);
    k_gather1<<<gN, TPB, 0, stream>>>(off, src_sorted, dinv, x, xp, n);
    k_f1<<<(n * HID + TPB - 1) / TPB, TPB, 0, stream>>>(xp, W1, b1, f1, n);
    k_gather2<<<(n + 3) / 4, 256, 0, stream>>>(off, src_sorted, dinv, f1, acc2, n);
    k_mm2_pool<<<(n + TILE_N - 1) / TILE_N, GEMM_TPB, 0, stream>>>(acc2, W2, b2, batch, out, n);
    k_div<<<(out_size + TPB - 1) / TPB, TPB, 0, stream>>>(out, cnt, out_size);
}

// Round 9
// 497.883 us; speedup vs baseline: 1.5511x; 1.1038x over previous
//
#include <hip/hip_runtime.h>

#define TPB 256
#define HID 128
#define IN_C 4
#define SCAN_TPB 256
#define SCAN_CHUNK 1024   // 4 elements per thread
#define GEMM_TPB 256
#define TILE_N 64

// ---------------------------------------------------------------------------
// K0: zero deg_i and out
__global__ void k_init(int* deg_i, float* out, int n, int outsz) {
    int i = blockIdx.x * blockDim.x + threadIdx.x;
    if (i < n) deg_i[i] = 0;
    if (i < outsz) out[i] = 0.0f;
}

// K1: in-degree histogram (int atomics, random dsts -> low contention)
__global__ void k_hist(const int* __restrict__ dst, int* deg_i, int e) {
    int i = blockIdx.x * blockDim.x + threadIdx.x;
    if (i < e) atomicAdd(&deg_i[dst[i]], 1);
}

// K2: per-graph node counts via binary search on sorted batch (no atomics)
__global__ void k_cnt(const int* __restrict__ batch, int* cnt, int n, int bg) {
    int b = blockIdx.x * blockDim.x + threadIdx.x;
    if (b >= bg) return;
    int lo0 = 0, hi0 = n;
    while (lo0 < hi0) { int m = (lo0 + hi0) >> 1; if (batch[m] < b) lo0 = m + 1; else hi0 = m; }
    int lo1 = lo0, hi1 = n;
    while (lo1 < hi1) { int m = (lo1 + hi1) >> 1; if (batch[m] < b + 1) lo1 = m + 1; else hi1 = m; }
    cnt[b] = lo1 - lo0;
}

// K3a: per-block sums of deg_i (block = SCAN_CHUNK elements)
__global__ __launch_bounds__(SCAN_TPB) void k_scan_part(const int* __restrict__ deg_i,
                                                        int* bsum, int n) {
    __shared__ int red[SCAN_TPB];
    int b = blockIdx.x, t = threadIdx.x;
    int base = b * SCAN_CHUNK + t * 4;
    int s = 0;
#pragma unroll
    for (int k = 0; k < 4; k++) {
        int i = base + k;
        if (i < n) s += deg_i[i];
    }
    red[t] = s;
    __syncthreads();
    for (int d = SCAN_TPB / 2; d > 0; d >>= 1) {
        if (t < d) red[t] += red[t + d];
        __syncthreads();
    }
    if (t == 0) bsum[b] = red[0];
}

// K3b: single-block exclusive scan of block sums
__global__ __launch_bounds__(1024) void k_scan_bsum(int* bsum, int nb) {
    __shared__ int red[1024];
    int t = threadIdx.x;
    int carry = 0;
    for (int base = 0; base < nb; base += 1024) {
        int i = base + t;
        int v = (i < nb) ? bsum[i] : 0;
        red[t] = v;
        __syncthreads();
        for (int d = 1; d < 1024; d <<= 1) {
            int x = 0;
            if (t >= d) x = red[t - d];
            __syncthreads();
            if (t >= d) red[t] += x;
            __syncthreads();
        }
        int tot = red[1023];
        if (i < nb) bsum[i] = carry + red[t] - v;   // exclusive
        carry += tot;
        __syncthreads();
    }
}

// K3c: final scan pass -> off, cursor; fused dinv = rsqrt(deg+1)
__global__ __launch_bounds__(SCAN_TPB) void k_scan_final(
        const int* __restrict__ deg_i, const int* __restrict__ bsum,
        int* off, int* cursor, float* dinv, int n, int e) {
    __shared__ int red[SCAN_TPB];
    int b = blockIdx.x, t = threadIdx.x;
    int base = b * SCAN_CHUNK + t * 4;
    int v[4];
    int s = 0;
#pragma unroll
    for (int k = 0; k < 4; k++) {
        int i = base + k;
        v[k] = (i < n) ? deg_i[i] : 0;
        s += v[k];
    }
    red[t] = s;
    __syncthreads();
    for (int d = 1; d < SCAN_TPB; d <<= 1) {
        int x = 0;
        if (t >= d) x = red[t - d];
        __syncthreads();
        if (t >= d) red[t] += x;
        __syncthreads();
    }
    int run = bsum[b] + red[t] - s;
#pragma unroll
    for (int k = 0; k < 4; k++) {
        int i = base + k;
        if (i < n) {
            off[i] = run;
            cursor[i] = run;
            dinv[i] = rsqrtf((float)v[k] + 1.0f);
            run += v[k];
        }
    }
    if (b == 0 && t == 0) off[n] = e;
}

// K5: counting-sort fill, XCD-localized.
// 8 concurrent filtered passes: block b covers edge chunk (b>>3) but only
// edges whose dst lands in node-slice (b&7). With round-robin block->XCD
// dispatch, each src_sorted/cursor slice is written by ONE XCD -> the ~16
// 4B writes per 64B line merge in that L2 instead of flushing to HBM each
// time (R8: WRITE_SIZE was 105 MB for a 6.4 MB array). Correct under any
// mapping (device-scope atomics); the XCD affinity is perf-only.
__global__ void k_fillpos(const int* __restrict__ src, const int* __restrict__ dst,
                          int* cursor, int* src_sorted, int e, int n) {
    int pass = blockIdx.x & 7;
    int i = (blockIdx.x >> 3) * blockDim.x + threadIdx.x;
    if (i >= e) return;
    int rlo = (int)(((long)n * pass) >> 3);
    int rhi = (int)(((long)n * (pass + 1)) >> 3);
    int d = dst[i];
    if (d >= rlo && d < rhi) {
        int p = atomicAdd(&cursor[d], 1);
        src_sorted[p] = src[i];
    }
}

// K6: layer-1 propagation as gather on raw 4-channel x; unroll x4 for MLP
__global__ void k_gather1(const int* __restrict__ off, const int* __restrict__ src_sorted,
                          const float* __restrict__ dinv, const float* __restrict__ x,
                          float* xp, int n) {
    int v = blockIdx.x * blockDim.x + threadIdx.x;
    if (v >= n) return;
    float dv = dinv[v];
    const float4* x4 = (const float4*)x;
    float4 xv = x4[v];
    float sl = dv * dv;
    float4 A = make_float4(sl * xv.x, sl * xv.y, sl * xv.z, sl * xv.w);
    float4 B = make_float4(0.f, 0.f, 0.f, 0.f);
    float4 C = make_float4(0.f, 0.f, 0.f, 0.f);
    float4 D = make_float4(0.f, 0.f, 0.f, 0.f);
    int e0 = off[v], e1 = off[v + 1];
    int e = e0;
    for (; e + 4 <= e1; e += 4) {
        int s0 = src_sorted[e], s1 = src_sorted[e + 1];
        int s2 = src_sorted[e + 2], s3 = src_sorted[e + 3];
        float n0 = dinv[s0] * dv, n1 = dinv[s1] * dv;
        float n2 = dinv[s2] * dv, n3 = dinv[s3] * dv;
        float4 r0 = x4[s0], r1 = x4[s1], r2 = x4[s2], r3 = x4[s3];
        A.x = fmaf(n0, r0.x, A.x); A.y = fmaf(n0, r0.y, A.y);
        A.z = fmaf(n0, r0.z, A.z); A.w = fmaf(n0, r0.w, A.w);
        B.x = fmaf(n1, r1.x, B.x); B.y = fmaf(n1, r1.y, B.y);
        B.z = fmaf(n1, r1.z, B.z); B.w = fmaf(n1, r1.w, B.w);
        C.x = fmaf(n2, r2.x, C.x); C.y = fmaf(n2, r2.y, C.y);
        C.z = fmaf(n2, r2.z, C.z); C.w = fmaf(n2, r2.w, C.w);
        D.x = fmaf(n3, r3.x, D.x); D.y = fmaf(n3, r3.y, D.y);
        D.z = fmaf(n3, r3.z, D.z); D.w = fmaf(n3, r3.w, D.w);
    }
    for (; e < e1; e++) {
        int s = src_sorted[e];
        float nm = dinv[s] * dv;
        float4 r = x4[s];
        A.x = fmaf(nm, r.x, A.x); A.y = fmaf(nm, r.y, A.y);
        A.z = fmaf(nm, r.z, A.z); A.w = fmaf(nm, r.w, A.w);
    }
    float4 o;
    o.x = (A.x + B.x) + (C.x + D.x);
    o.y = (A.y + B.y) + (C.y + D.y);
    o.z = (A.z + B.z) + (C.z + D.z);
    o.w = (A.w + B.w) + (C.w + D.w);
    ((float4*)xp)[v] = o;
}

// K7: f1 = relu(xp @ W1 + b1)
__global__ void k_f1(const float* __restrict__ xp, const float* __restrict__ W1,
                     const float* __restrict__ b1, float* f1, int n) {
    int i = blockIdx.x * blockDim.x + threadIdx.x;
    if (i >= n * HID) return;
    int v = i >> 7, c = i & (HID - 1);
    const float4* xr = (const float4*)(xp + v * IN_C);
    float4 xv = *xr;
    float s = fmaf(xv.x, W1[c],
              fmaf(xv.y, W1[HID + c],
              fmaf(xv.z, W1[2 * HID + c],
              fmaf(xv.w, W1[3 * HID + c], b1[c]))));
    f1[i] = s > 0.0f ? s : 0.0f;
}

// K8: layer-2 gather: one WAVE per node, float2 per lane, x4 unrolled MLP
__global__ __launch_bounds__(256) void k_gather2(
        const int* __restrict__ off, const int* __restrict__ src_sorted,
        const float* __restrict__ dinv, const float* __restrict__ f1,
        float* acc2, int n) {
    int wv = threadIdx.x >> 6;           // wave id 0..3
    int ln = threadIdx.x & 63;           // lane
    int v = blockIdx.x * 4 + wv;
    if (v >= n) return;
    float dv = dinv[v];
    const float2* f2 = (const float2*)f1;   // row = 64 float2
    float2 self = f2[(size_t)v * 64 + ln];
    float sl = dv * dv;
    float ax = sl * self.x, ay = sl * self.y;
    float bx = 0.f, by = 0.f, cx = 0.f, cy = 0.f, dx = 0.f, dy = 0.f;
    int e0 = off[v], e1 = off[v + 1];
    int e = e0;
    for (; e + 4 <= e1; e += 4) {
        int s0 = src_sorted[e],     s1 = src_sorted[e + 1];
        int s2 = src_sorted[e + 2], s3 = src_sorted[e + 3];
        float n0 = dinv[s0] * dv, n1 = dinv[s1] * dv;
        float n2 = dinv[s2] * dv, n3 = dinv[s3] * dv;
        float2 r0 = f2[(size_t)s0 * 64 + ln];
        float2 r1 = f2[(size_t)s1 * 64 + ln];
        float2 r2 = f2[(size_t)s2 * 64 + ln];
        float2 r3 = f2[(size_t)s3 * 64 + ln];
        ax = fmaf(n0, r0.x, ax); ay = fmaf(n0, r0.y, ay);
        bx = fmaf(n1, r1.x, bx); by = fmaf(n1, r1.y, by);
        cx = fmaf(n2, r2.x, cx); cy = fmaf(n2, r2.y, cy);
        dx = fmaf(n3, r3.x, dx); dy = fmaf(n3, r3.y, dy);
    }
    for (; e < e1; e++) {
        int s = src_sorted[e];
        float nm = dinv[s] * dv;
        float2 r = f2[(size_t)s * 64 + ln];
        ax = fmaf(nm, r.x, ax); ay = fmaf(nm, r.y, ay);
    }
    float2 o;
    o.x = (ax + bx) + (cx + dx);
    o.y = (ay + by) + (cy + dy);
    ((float2*)acc2)[(size_t)v * 64 + ln] = o;
}

// K9: tiled GEMM + fused bias/ReLU/segment-pool.
// A-tile in LDS (33.8 KB, 4 blocks/CU); W2 from global (L2-resident) with an
// explicit register double-buffer; A-reads batched (8 ds_read_b128) per iter.
__global__ __launch_bounds__(GEMM_TPB, 4) void k_mm2_pool(
        const float* __restrict__ acc2, const float* __restrict__ W2,
        const float* __restrict__ b2, const int* __restrict__ batch,
        float* out, int n) {
    __shared__ float As[TILE_N][132];   // node-major, pad 128->132 words
    __shared__ int bch[TILE_N];

    int t = threadIdx.x;
    int v0 = blockIdx.x * TILE_N;
    int cg = t & 31;          // channel quad: channels 4cg..4cg+3
    int ng = t >> 5;          // node octet: nodes 8ng..8ng+7
    int nd0 = ng * 8;

    // stage A tile: coalesced float4 row copy
#pragma unroll
    for (int j = 0; j < 8; j++) {
        int fi = t + GEMM_TPB * j;          // 0..2047
        int nd = fi >> 5, kq = fi & 31;
        int v = v0 + nd;
        if (v < n) {
            float4 a = ((const float4*)acc2)[(size_t)v * 32 + kq];
            *(float4*)&As[nd][kq * 4] = a;
        }
    }
    if (t < TILE_N) {
        int v = v0 + t;
        bch[t] = (v < n) ? batch[v] : -1;
    }
    __syncthreads();

    float4 acc[8];
#pragma unroll
    for (int i = 0; i < 8; i++) acc[i] = make_float4(0.f, 0.f, 0.f, 0.f);

    const float4* W2v = (const float4*)W2;   // row k = 32 float4

    float4 w[4];
#pragma unroll
    for (int j = 0; j < 4; j++) w[j] = W2v[j * 32 + cg];

    for (int k4 = 0; k4 < 32; k4++) {
        int k0 = k4 * 4;
        // prefetch next iteration's W (clamped index, unconditional)
        int kn = (k4 < 31) ? (k0 + 4) : 0;
        float4 wn[4];
#pragma unroll
        for (int j = 0; j < 4; j++) wn[j] = W2v[(kn + j) * 32 + cg];
        // batch the 8 LDS A-reads
        float4 a[8];
#pragma unroll
        for (int i = 0; i < 8; i++) a[i] = *(float4*)&As[nd0 + i][k0];
#pragma unroll
        for (int i = 0; i < 8; i++) {
            acc[i].x = fmaf(a[i].x, w[0].x, acc[i].x);
            acc[i].y = fmaf(a[i].x, w[0].y, acc[i].y);
            acc[i].z = fmaf(a[i].x, w[0].z, acc[i].z);
            acc[i].w = fmaf(a[i].x, w[0].w, acc[i].w);
            acc[i].x = fmaf(a[i].y, w[1].x, acc[i].x);
            acc[i].y = fmaf(a[i].y, w[1].y, acc[i].y);
            acc[i].z = fmaf(a[i].y, w[1].z, acc[i].z);
            acc[i].w = fmaf(a[i].y, w[1].w, acc[i].w);
            acc[i].x = fmaf(a[i].z, w[2].x, acc[i].x);
            acc[i].y = fmaf(a[i].z, w[2].y, acc[i].y);
            acc[i].z = fmaf(a[i].z, w[2].z, acc[i].z);
            acc[i].w = fmaf(a[i].z, w[2].w, acc[i].w);
            acc[i].x = fmaf(a[i].w, w[3].x, acc[i].x);
            acc[i].y = fmaf(a[i].w, w[3].y, acc[i].y);
            acc[i].z = fmaf(a[i].w, w[3].z, acc[i].z);
            acc[i].w = fmaf(a[i].w, w[3].w, acc[i].w);
        }
#pragma unroll
        for (int j = 0; j < 4; j++) w[j] = wn[j];
    }

    // epilogue: bias + relu + segment run-accumulate (batch sorted)
    float4 bb = *(const float4*)(b2 + cg * 4);
    int curb = -1;
    float4 run = make_float4(0.f, 0.f, 0.f, 0.f);
    for (int i = 0; i < 8; i++) {
        int b = bch[nd0 + i];
        if (b < 0) break;                    // invalid nodes are a suffix
        if (b != curb) {
            if (curb >= 0) {
                float* o = out + (size_t)curb * HID + cg * 4;
                atomicAdd(o + 0, run.x); atomicAdd(o + 1, run.y);
                atomicAdd(o + 2, run.z); atomicAdd(o + 3, run.w);
            }
            run = make_float4(0.f, 0.f, 0.f, 0.f);
            curb = b;
        }
        float fx = acc[i].x + bb.x; run.x += fx > 0.f ? fx : 0.f;
        float fy = acc[i].y + bb.y; run.y += fy > 0.f ? fy : 0.f;
        float fz = acc[i].z + bb.z; run.z += fz > 0.f ? fz : 0.f;
        float fw = acc[i].w + bb.w; run.w += fw > 0.f ? fw : 0.f;
    }
    if (curb >= 0) {
        float* o = out + (size_t)curb * HID + cg * 4;
        atomicAdd(o + 0, run.x); atomicAdd(o + 1, run.y);
        atomicAdd(o + 2, run.z); atomicAdd(o + 3, run.w);
    }
}

// K10: out[b][c] /= max(cnt[b], 1)
__global__ void k_div(float* out, const int* __restrict__ cnt, int outsz) {
    int i = blockIdx.x * blockDim.x + threadIdx.x;
    if (i < outsz) {
        int b = i >> 7;
        float cf = (float)cnt[b];
        out[i] = out[i] / fmaxf(cf, 1.0f);
    }
}

extern "C" void kernel_launch(void* const* d_in, const int* in_sizes, int n_in,
                              void* d_out, int out_size, void* d_ws, size_t ws_size,
                              hipStream_t stream) {
    const float* x   = (const float*)d_in[0];
    const int* ei    = (const int*)d_in[1];   // [2, E] flat: src then dst
    const int* batch = (const int*)d_in[2];
    const float* W1  = (const float*)d_in[3];
    const float* b1  = (const float*)d_in[4];
    const float* W2  = (const float*)d_in[5];
    const float* b2  = (const float*)d_in[6];
    float* out = (float*)d_out;

    int n  = in_sizes[0] / IN_C;
    int e  = in_sizes[1] / 2;
    int bg = out_size / HID;
    const int* src = ei;
    const int* dst = ei + e;

    size_t off_b = 0;
    char* base = (char*)d_ws;
    auto carve = [&](size_t bytes) -> void* {
        void* p = base + off_b;
        off_b += (bytes + 255) & ~(size_t)255;
        return p;
    };
    int nbScan = (n + SCAN_CHUNK - 1) / SCAN_CHUNK;
    int*   deg_i      = (int*)carve((size_t)n * 4);
    int*   off        = (int*)carve((size_t)(n + 1) * 4);
    int*   cursor     = (int*)carve((size_t)n * 4);
    int*   src_sorted = (int*)carve((size_t)e * 4);
    float* dinv       = (float*)carve((size_t)n * 4);
    int*   bsum       = (int*)carve((size_t)nbScan * 4);
    float* xp         = (float*)carve((size_t)n * IN_C * 4);
    float* f1         = (float*)carve((size_t)n * HID * 4);
    float* acc2       = (float*)carve((size_t)n * HID * 4);
    int*   cnt        = (int*)carve((size_t)bg * 4);
    (void)ws_size;

    int gN = (n + TPB - 1) / TPB;
    int gE = (e + TPB - 1) / TPB;

    k_init<<<gN, TPB, 0, stream>>>(deg_i, out, n, out_size);
    k_hist<<<gE, TPB, 0, stream>>>(dst, deg_i, e);
    k_cnt<<<1, 64, 0, stream>>>(batch, cnt, n, bg);
    k_scan_part<<<nbScan, SCAN_TPB, 0, stream>>>(deg_i, bsum, n);
    k_scan_bsum<<<1, 1024, 0, stream>>>(bsum, nbScan);
    k_scan_final<<<nbScan, SCAN_TPB, 0, stream>>>(deg_i, bsum, off, cursor, dinv, n, e);
    k_fillpos<<<gE * 8, TPB, 0, stream>>>(src, dst, cursor, src_sorted, e, n);
    k_gather1<<<gN, TPB, 0, stream>>>(off, src_sorted, dinv, x, xp, n);
    k_f1<<<(n * HID + TPB - 1) / TPB, TPB, 0, stream>>>(xp, W1, b1, f1, n);
    k_gather2<<<(n + 3) / 4, 256, 0, stream>>>(off, src_sorted, dinv, f1, acc2, n);
    k_mm2_pool<<<(n + TILE_N - 1) / TILE_N, GEMM_TPB, 0, stream>>>(acc2, W2, b2, batch, out, n);
    k_div<<<(out_size + TPB - 1) / TPB, TPB, 0, stream>>>(out, cnt, out_size);
}

// Round 10
// 440.039 us; speedup vs baseline: 1.7550x; 1.1315x over previous
//
#include <hip/hip_runtime.h>

#define TPB 256
#define HID 128
#define IN_C 4
#define SCAN_TPB 256
#define SCAN_CHUNK 1024   // 4 elements per thread
#define GEMM_TPB 256
#define TILE_N 64

// bf16 helpers: pack with RNE, unpack with shift (values finite, no NaN)
__device__ __forceinline__ unsigned f2bf(float f) {
    unsigned u = __float_as_uint(f);
    return (u + 0x7fffu + ((u >> 16) & 1u)) >> 16;
}
__device__ __forceinline__ float bf_lo(unsigned u) { return __uint_as_float(u << 16); }
__device__ __forceinline__ float bf_hi(unsigned u) { return __uint_as_float(u & 0xffff0000u); }

// ---------------------------------------------------------------------------
// K0: zero deg_i and out
__global__ void k_init(int* deg_i, float* out, int n, int outsz) {
    int i = blockIdx.x * blockDim.x + threadIdx.x;
    if (i < n) deg_i[i] = 0;
    if (i < outsz) out[i] = 0.0f;
}

// K1: in-degree histogram (int atomics, random dsts -> low contention)
__global__ void k_hist(const int* __restrict__ dst, int* deg_i, int e) {
    int i = blockIdx.x * blockDim.x + threadIdx.x;
    if (i < e) atomicAdd(&deg_i[dst[i]], 1);
}

// K2: per-graph node counts via binary search on sorted batch (no atomics)
__global__ void k_cnt(const int* __restrict__ batch, int* cnt, int n, int bg) {
    int b = blockIdx.x * blockDim.x + threadIdx.x;
    if (b >= bg) return;
    int lo0 = 0, hi0 = n;
    while (lo0 < hi0) { int m = (lo0 + hi0) >> 1; if (batch[m] < b) lo0 = m + 1; else hi0 = m; }
    int lo1 = lo0, hi1 = n;
    while (lo1 < hi1) { int m = (lo1 + hi1) >> 1; if (batch[m] < b + 1) lo1 = m + 1; else hi1 = m; }
    cnt[b] = lo1 - lo0;
}

// K3a: per-block sums of deg_i (block = SCAN_CHUNK elements)
__global__ __launch_bounds__(SCAN_TPB) void k_scan_part(const int* __restrict__ deg_i,
                                                        int* bsum, int n) {
    __shared__ int red[SCAN_TPB];
    int b = blockIdx.x, t = threadIdx.x;
    int base = b * SCAN_CHUNK + t * 4;
    int s = 0;
#pragma unroll
    for (int k = 0; k < 4; k++) {
        int i = base + k;
        if (i < n) s += deg_i[i];
    }
    red[t] = s;
    __syncthreads();
    for (int d = SCAN_TPB / 2; d > 0; d >>= 1) {
        if (t < d) red[t] += red[t + d];
        __syncthreads();
    }
    if (t == 0) bsum[b] = red[0];
}

// K3b: single-block exclusive scan of block sums
__global__ __launch_bounds__(1024) void k_scan_bsum(int* bsum, int nb) {
    __shared__ int red[1024];
    int t = threadIdx.x;
    int carry = 0;
    for (int base = 0; base < nb; base += 1024) {
        int i = base + t;
        int v = (i < nb) ? bsum[i] : 0;
        red[t] = v;
        __syncthreads();
        for (int d = 1; d < 1024; d <<= 1) {
            int x = 0;
            if (t >= d) x = red[t - d];
            __syncthreads();
            if (t >= d) red[t] += x;
            __syncthreads();
        }
        int tot = red[1023];
        if (i < nb) bsum[i] = carry + red[t] - v;   // exclusive
        carry += tot;
        __syncthreads();
    }
}

// K3c: final scan pass -> off, cursor; fused dinv = rsqrt(deg+1)
__global__ __launch_bounds__(SCAN_TPB) void k_scan_final(
        const int* __restrict__ deg_i, const int* __restrict__ bsum,
        int* off, int* cursor, float* dinv, int n, int e) {
    __shared__ int red[SCAN_TPB];
    int b = blockIdx.x, t = threadIdx.x;
    int base = b * SCAN_CHUNK + t * 4;
    int v[4];
    int s = 0;
#pragma unroll
    for (int k = 0; k < 4; k++) {
        int i = base + k;
        v[k] = (i < n) ? deg_i[i] : 0;
        s += v[k];
    }
    red[t] = s;
    __syncthreads();
    for (int d = 1; d < SCAN_TPB; d <<= 1) {
        int x = 0;
        if (t >= d) x = red[t - d];
        __syncthreads();
        if (t >= d) red[t] += x;
        __syncthreads();
    }
    int run = bsum[b] + red[t] - s;
#pragma unroll
    for (int k = 0; k < 4; k++) {
        int i = base + k;
        if (i < n) {
            off[i] = run;
            cursor[i] = run;
            dinv[i] = rsqrtf((float)v[k] + 1.0f);
            run += v[k];
        }
    }
    if (b == 0 && t == 0) off[n] = e;
}

// K5: counting-sort fill, XCD-localized (8 filtered passes; see R9 notes)
__global__ void k_fillpos(const int* __restrict__ src, const int* __restrict__ dst,
                          int* cursor, int* src_sorted, int e, int n) {
    int pass = blockIdx.x & 7;
    int i = (blockIdx.x >> 3) * blockDim.x + threadIdx.x;
    if (i >= e) return;
    int rlo = (int)(((long)n * pass) >> 3);
    int rhi = (int)(((long)n * (pass + 1)) >> 3);
    int d = dst[i];
    if (d >= rlo && d < rhi) {
        int p = atomicAdd(&cursor[d], 1);
        src_sorted[p] = src[i];
    }
}

// K6: layer-1 propagation as gather on raw 4-channel x; unroll x4 for MLP
__global__ void k_gather1(const int* __restrict__ off, const int* __restrict__ src_sorted,
                          const float* __restrict__ dinv, const float* __restrict__ x,
                          float* xp, int n) {
    int v = blockIdx.x * blockDim.x + threadIdx.x;
    if (v >= n) return;
    float dv = dinv[v];
    const float4* x4 = (const float4*)x;
    float4 xv = x4[v];
    float sl = dv * dv;
    float4 A = make_float4(sl * xv.x, sl * xv.y, sl * xv.z, sl * xv.w);
    float4 B = make_float4(0.f, 0.f, 0.f, 0.f);
    float4 C = make_float4(0.f, 0.f, 0.f, 0.f);
    float4 D = make_float4(0.f, 0.f, 0.f, 0.f);
    int e0 = off[v], e1 = off[v + 1];
    int e = e0;
    for (; e + 4 <= e1; e += 4) {
        int s0 = src_sorted[e], s1 = src_sorted[e + 1];
        int s2 = src_sorted[e + 2], s3 = src_sorted[e + 3];
        float n0 = dinv[s0] * dv, n1 = dinv[s1] * dv;
        float n2 = dinv[s2] * dv, n3 = dinv[s3] * dv;
        float4 r0 = x4[s0], r1 = x4[s1], r2 = x4[s2], r3 = x4[s3];
        A.x = fmaf(n0, r0.x, A.x); A.y = fmaf(n0, r0.y, A.y);
        A.z = fmaf(n0, r0.z, A.z); A.w = fmaf(n0, r0.w, A.w);
        B.x = fmaf(n1, r1.x, B.x); B.y = fmaf(n1, r1.y, B.y);
        B.z = fmaf(n1, r1.z, B.z); B.w = fmaf(n1, r1.w, B.w);
        C.x = fmaf(n2, r2.x, C.x); C.y = fmaf(n2, r2.y, C.y);
        C.z = fmaf(n2, r2.z, C.z); C.w = fmaf(n2, r2.w, C.w);
        D.x = fmaf(n3, r3.x, D.x); D.y = fmaf(n3, r3.y, D.y);
        D.z = fmaf(n3, r3.z, D.z); D.w = fmaf(n3, r3.w, D.w);
    }
    for (; e < e1; e++) {
        int s = src_sorted[e];
        float nm = dinv[s] * dv;
        float4 r = x4[s];
        A.x = fmaf(nm, r.x, A.x); A.y = fmaf(nm, r.y, A.y);
        A.z = fmaf(nm, r.z, A.z); A.w = fmaf(nm, r.w, A.w);
    }
    float4 o;
    o.x = (A.x + B.x) + (C.x + D.x);
    o.y = (A.y + B.y) + (C.y + D.y);
    o.z = (A.z + B.z) + (C.z + D.z);
    o.w = (A.w + B.w) + (C.w + D.w);
    ((float4*)xp)[v] = o;
}

// K7: f1 = relu(xp @ W1 + b1), output packed bf16 (2 ch per uint).
// Row = 64 uints = 256 B -> one dword per lane in the gather.
__global__ void k_f1(const float* __restrict__ xp, const float* __restrict__ W1,
                     const float* __restrict__ b1, unsigned* f1p, int n) {
    int i = blockIdx.x * blockDim.x + threadIdx.x;
    if (i >= n * 64) return;
    int v = i >> 6, cp = i & 63;
    int c0 = cp * 2, c1 = c0 + 1;
    float4 xv = *(const float4*)(xp + v * IN_C);
    float s0 = fmaf(xv.x, W1[c0],
               fmaf(xv.y, W1[HID + c0],
               fmaf(xv.z, W1[2 * HID + c0],
               fmaf(xv.w, W1[3 * HID + c0], b1[c0]))));
    float s1 = fmaf(xv.x, W1[c1],
               fmaf(xv.y, W1[HID + c1],
               fmaf(xv.z, W1[2 * HID + c1],
               fmaf(xv.w, W1[3 * HID + c1], b1[c1]))));
    s0 = s0 > 0.0f ? s0 : 0.0f;
    s1 = s1 > 0.0f ? s1 : 0.0f;
    f1p[i] = f2bf(s0) | (f2bf(s1) << 16);
}

// K8: layer-2 gather on bf16 rows: one WAVE per node, one dword (2 ch) per
// lane, x4 unrolled. Halves the random-gather traffic vs fp32 (R9: 415 MB
// L2-fill at 3.4 TB/s was the bottleneck).
__global__ __launch_bounds__(256) void k_gather2(
        const int* __restrict__ off, const int* __restrict__ src_sorted,
        const float* __restrict__ dinv, const unsigned* __restrict__ f1p,
        float* acc2, int n) {
    int wv = threadIdx.x >> 6;           // wave id 0..3
    int ln = threadIdx.x & 63;           // lane: channels 2ln, 2ln+1
    int v = blockIdx.x * 4 + wv;
    if (v >= n) return;
    float dv = dinv[v];
    unsigned su = f1p[(size_t)v * 64 + ln];
    float sl = dv * dv;
    float ax = sl * bf_lo(su), ay = sl * bf_hi(su);
    float bx = 0.f, by = 0.f, cx = 0.f, cy = 0.f, dx = 0.f, dy = 0.f;
    int e0 = off[v], e1 = off[v + 1];
    int e = e0;
    for (; e + 4 <= e1; e += 4) {
        int s0 = src_sorted[e],     s1 = src_sorted[e + 1];
        int s2 = src_sorted[e + 2], s3 = src_sorted[e + 3];
        float n0 = dinv[s0] * dv, n1 = dinv[s1] * dv;
        float n2 = dinv[s2] * dv, n3 = dinv[s3] * dv;
        unsigned u0 = f1p[(size_t)s0 * 64 + ln];
        unsigned u1 = f1p[(size_t)s1 * 64 + ln];
        unsigned u2 = f1p[(size_t)s2 * 64 + ln];
        unsigned u3 = f1p[(size_t)s3 * 64 + ln];
        ax = fmaf(n0, bf_lo(u0), ax); ay = fmaf(n0, bf_hi(u0), ay);
        bx = fmaf(n1, bf_lo(u1), bx); by = fmaf(n1, bf_hi(u1), by);
        cx = fmaf(n2, bf_lo(u2), cx); cy = fmaf(n2, bf_hi(u2), cy);
        dx = fmaf(n3, bf_lo(u3), dx); dy = fmaf(n3, bf_hi(u3), dy);
    }
    for (; e < e1; e++) {
        int s = src_sorted[e];
        float nm = dinv[s] * dv;
        unsigned u = f1p[(size_t)s * 64 + ln];
        ax = fmaf(nm, bf_lo(u), ax); ay = fmaf(nm, bf_hi(u), ay);
    }
    float2 o;
    o.x = (ax + bx) + (cx + dx);
    o.y = (ay + by) + (cy + dy);
    ((float2*)acc2)[(size_t)v * 64 + ln] = o;
}

// K9: tiled GEMM + fused bias/ReLU/segment-pool (unchanged from R8)
__global__ __launch_bounds__(GEMM_TPB, 4) void k_mm2_pool(
        const float* __restrict__ acc2, const float* __restrict__ W2,
        const float* __restrict__ b2, const int* __restrict__ batch,
        float* out, int n) {
    __shared__ float As[TILE_N][132];   // node-major, pad 128->132 words
    __shared__ int bch[TILE_N];

    int t = threadIdx.x;
    int v0 = blockIdx.x * TILE_N;
    int cg = t & 31;          // channel quad: channels 4cg..4cg+3
    int ng = t >> 5;          // node octet: nodes 8ng..8ng+7
    int nd0 = ng * 8;

#pragma unroll
    for (int j = 0; j < 8; j++) {
        int fi = t + GEMM_TPB * j;          // 0..2047
        int nd = fi >> 5, kq = fi & 31;
        int v = v0 + nd;
        if (v < n) {
            float4 a = ((const float4*)acc2)[(size_t)v * 32 + kq];
            *(float4*)&As[nd][kq * 4] = a;
        }
    }
    if (t < TILE_N) {
        int v = v0 + t;
        bch[t] = (v < n) ? batch[v] : -1;
    }
    __syncthreads();

    float4 acc[8];
#pragma unroll
    for (int i = 0; i < 8; i++) acc[i] = make_float4(0.f, 0.f, 0.f, 0.f);

    const float4* W2v = (const float4*)W2;   // row k = 32 float4

    float4 w[4];
#pragma unroll
    for (int j = 0; j < 4; j++) w[j] = W2v[j * 32 + cg];

    for (int k4 = 0; k4 < 32; k4++) {
        int k0 = k4 * 4;
        int kn = (k4 < 31) ? (k0 + 4) : 0;
        float4 wn[4];
#pragma unroll
        for (int j = 0; j < 4; j++) wn[j] = W2v[(kn + j) * 32 + cg];
        float4 a[8];
#pragma unroll
        for (int i = 0; i < 8; i++) a[i] = *(float4*)&As[nd0 + i][k0];
#pragma unroll
        for (int i = 0; i < 8; i++) {
            acc[i].x = fmaf(a[i].x, w[0].x, acc[i].x);
            acc[i].y = fmaf(a[i].x, w[0].y, acc[i].y);
            acc[i].z = fmaf(a[i].x, w[0].z, acc[i].z);
            acc[i].w = fmaf(a[i].x, w[0].w, acc[i].w);
            acc[i].x = fmaf(a[i].y, w[1].x, acc[i].x);
            acc[i].y = fmaf(a[i].y, w[1].y, acc[i].y);
            acc[i].z = fmaf(a[i].y, w[1].z, acc[i].z);
            acc[i].w = fmaf(a[i].y, w[1].w, acc[i].w);
            acc[i].x = fmaf(a[i].z, w[2].x, acc[i].x);
            acc[i].y = fmaf(a[i].z, w[2].y, acc[i].y);
            acc[i].z = fmaf(a[i].z, w[2].z, acc[i].z);
            acc[i].w = fmaf(a[i].z, w[2].w, acc[i].w);
            acc[i].x = fmaf(a[i].w, w[3].x, acc[i].x);
            acc[i].y = fmaf(a[i].w, w[3].y, acc[i].y);
            acc[i].z = fmaf(a[i].w, w[3].z, acc[i].z);
            acc[i].w = fmaf(a[i].w, w[3].w, acc[i].w);
        }
#pragma unroll
        for (int j = 0; j < 4; j++) w[j] = wn[j];
    }

    // epilogue: bias + relu + segment run-accumulate (batch sorted)
    float4 bb = *(const float4*)(b2 + cg * 4);
    int curb = -1;
    float4 run = make_float4(0.f, 0.f, 0.f, 0.f);
    for (int i = 0; i < 8; i++) {
        int b = bch[nd0 + i];
        if (b < 0) break;
        if (b != curb) {
            if (curb >= 0) {
                float* o = out + (size_t)curb * HID + cg * 4;
                atomicAdd(o + 0, run.x); atomicAdd(o + 1, run.y);
                atomicAdd(o + 2, run.z); atomicAdd(o + 3, run.w);
            }
            run = make_float4(0.f, 0.f, 0.f, 0.f);
            curb = b;
        }
        float fx = acc[i].x + bb.x; run.x += fx > 0.f ? fx : 0.f;
        float fy = acc[i].y + bb.y; run.y += fy > 0.f ? fy : 0.f;
        float fz = acc[i].z + bb.z; run.z += fz > 0.f ? fz : 0.f;
        float fw = acc[i].w + bb.w; run.w += fw > 0.f ? fw : 0.f;
    }
    if (curb >= 0) {
        float* o = out + (size_t)curb * HID + cg * 4;
        atomicAdd(o + 0, run.x); atomicAdd(o + 1, run.y);
        atomicAdd(o + 2, run.z); atomicAdd(o + 3, run.w);
    }
}

// K10: out[b][c] /= max(cnt[b], 1)
__global__ void k_div(float* out, const int* __restrict__ cnt, int outsz) {
    int i = blockIdx.x * blockDim.x + threadIdx.x;
    if (i < outsz) {
        int b = i >> 7;
        float cf = (float)cnt[b];
        out[i] = out[i] / fmaxf(cf, 1.0f);
    }
}

extern "C" void kernel_launch(void* const* d_in, const int* in_sizes, int n_in,
                              void* d_out, int out_size, void* d_ws, size_t ws_size,
                              hipStream_t stream) {
    const float* x   = (const float*)d_in[0];
    const int* ei    = (const int*)d_in[1];   // [2, E] flat: src then dst
    const int* batch = (const int*)d_in[2];
    const float* W1  = (const float*)d_in[3];
    const float* b1  = (const float*)d_in[4];
    const float* W2  = (const float*)d_in[5];
    const float* b2  = (const float*)d_in[6];
    float* out = (float*)d_out;

    int n  = in_sizes[0] / IN_C;
    int e  = in_sizes[1] / 2;
    int bg = out_size / HID;
    const int* src = ei;
    const int* dst = ei + e;

    size_t off_b = 0;
    char* base = (char*)d_ws;
    auto carve = [&](size_t bytes) -> void* {
        void* p = base + off_b;
        off_b += (bytes + 255) & ~(size_t)255;
        return p;
    };
    int nbScan = (n + SCAN_CHUNK - 1) / SCAN_CHUNK;
    int*      deg_i      = (int*)carve((size_t)n * 4);
    int*      off        = (int*)carve((size_t)(n + 1) * 4);
    int*      cursor     = (int*)carve((size_t)n * 4);
    int*      src_sorted = (int*)carve((size_t)e * 4);
    float*    dinv       = (float*)carve((size_t)n * 4);
    int*      bsum       = (int*)carve((size_t)nbScan * 4);
    float*    xp         = (float*)carve((size_t)n * IN_C * 4);
    unsigned* f1p        = (unsigned*)carve((size_t)n * 64 * 4);   // bf16-packed
    float*    acc2       = (float*)carve((size_t)n * HID * 4);
    int*      cnt        = (int*)carve((size_t)bg * 4);
    (void)ws_size;

    int gN = (n + TPB - 1) / TPB;
    int gE = (e + TPB - 1) / TPB;

    k_init<<<gN, TPB, 0, stream>>>(deg_i, out, n, out_size);
    k_hist<<<gE, TPB, 0, stream>>>(dst, deg_i, e);
    k_cnt<<<1, 64, 0, stream>>>(batch, cnt, n, bg);
    k_scan_part<<<nbScan, SCAN_TPB, 0, stream>>>(deg_i, bsum, n);
    k_scan_bsum<<<1, 1024, 0, stream>>>(bsum, nbScan);
    k_scan_final<<<nbScan, SCAN_TPB, 0, stream>>>(deg_i, bsum, off, cursor, dinv, n, e);
    k_fillpos<<<gE * 8, TPB, 0, stream>>>(src, dst, cursor, src_sorted, e, n);
    k_gather1<<<gN, TPB, 0, stream>>>(off, src_sorted, dinv, x, xp, n);
    k_f1<<<(n * 64 + TPB - 1) / TPB, TPB, 0, stream>>>(xp, W1, b1, f1p, n);
    k_gather2<<<(n + 3) / 4, 256, 0, stream>>>(off, src_sorted, dinv, f1p, acc2, n);
    k_mm2_pool<<<(n + TILE_N - 1) / TILE_N, GEMM_TPB, 0, stream>>>(acc2, W2, b2, batch, out, n);
    k_div<<<(out_size + TPB - 1) / TPB, TPB, 0, stream>>>(out, cnt, out_size);
}

// Round 11
// 362.771 us; speedup vs baseline: 2.1288x; 1.2130x over previous
//
#include <hip/hip_runtime.h>

#define TPB 256
#define HID 128
#define IN_C 4
#define SCAN_TPB 256
#define SCAN_CHUNK 1024   // 4 elements per thread

typedef __attribute__((ext_vector_type(8))) short bf16x8;   // 8 bf16 = 4 VGPRs
typedef __attribute__((ext_vector_type(4))) float f32x4;

union FragU { uint4 u; bf16x8 b; };

// bf16 helpers: pack with RNE, unpack with shift (values finite, no NaN)
__device__ __forceinline__ unsigned f2bf(float f) {
    unsigned u = __float_as_uint(f);
    return (u + 0x7fffu + ((u >> 16) & 1u)) >> 16;
}
__device__ __forceinline__ float bf_lo(unsigned u) { return __uint_as_float(u << 16); }
__device__ __forceinline__ float bf_hi(unsigned u) { return __uint_as_float(u & 0xffff0000u); }

// ---------------------------------------------------------------------------
// K0: zero deg_i and out
__global__ void k_init(int* deg_i, float* out, int n, int outsz) {
    int i = blockIdx.x * blockDim.x + threadIdx.x;
    if (i < n) deg_i[i] = 0;
    if (i < outsz) out[i] = 0.0f;
}

// K1: in-degree histogram (int atomics, random dsts -> low contention)
__global__ void k_hist(const int* __restrict__ dst, int* deg_i, int e) {
    int i = blockIdx.x * blockDim.x + threadIdx.x;
    if (i < e) atomicAdd(&deg_i[dst[i]], 1);
}

// K2: per-graph node counts via binary search on sorted batch (no atomics)
__global__ void k_cnt(const int* __restrict__ batch, int* cnt, int n, int bg) {
    int b = blockIdx.x * blockDim.x + threadIdx.x;
    if (b >= bg) return;
    int lo0 = 0, hi0 = n;
    while (lo0 < hi0) { int m = (lo0 + hi0) >> 1; if (batch[m] < b) lo0 = m + 1; else hi0 = m; }
    int lo1 = lo0, hi1 = n;
    while (lo1 < hi1) { int m = (lo1 + hi1) >> 1; if (batch[m] < b + 1) lo1 = m + 1; else hi1 = m; }
    cnt[b] = lo1 - lo0;
}

// K3a: per-block sums of deg_i (block = SCAN_CHUNK elements)
__global__ __launch_bounds__(SCAN_TPB) void k_scan_part(const int* __restrict__ deg_i,
                                                        int* bsum, int n) {
    __shared__ int red[SCAN_TPB];
    int b = blockIdx.x, t = threadIdx.x;
    int base = b * SCAN_CHUNK + t * 4;
    int s = 0;
#pragma unroll
    for (int k = 0; k < 4; k++) {
        int i = base + k;
        if (i < n) s += deg_i[i];
    }
    red[t] = s;
    __syncthreads();
    for (int d = SCAN_TPB / 2; d > 0; d >>= 1) {
        if (t < d) red[t] += red[t + d];
        __syncthreads();
    }
    if (t == 0) bsum[b] = red[0];
}

// K3b: single-block exclusive scan of block sums
__global__ __launch_bounds__(1024) void k_scan_bsum(int* bsum, int nb) {
    __shared__ int red[1024];
    int t = threadIdx.x;
    int carry = 0;
    for (int base = 0; base < nb; base += 1024) {
        int i = base + t;
        int v = (i < nb) ? bsum[i] : 0;
        red[t] = v;
        __syncthreads();
        for (int d = 1; d < 1024; d <<= 1) {
            int x = 0;
            if (t >= d) x = red[t - d];
            __syncthreads();
            if (t >= d) red[t] += x;
            __syncthreads();
        }
        int tot = red[1023];
        if (i < nb) bsum[i] = carry + red[t] - v;   // exclusive
        carry += tot;
        __syncthreads();
    }
}

// K3c: final scan pass -> off, cursor; fused dinv = rsqrt(deg+1)
__global__ __launch_bounds__(SCAN_TPB) void k_scan_final(
        const int* __restrict__ deg_i, const int* __restrict__ bsum,
        int* off, int* cursor, float* dinv, int n, int e) {
    __shared__ int red[SCAN_TPB];
    int b = blockIdx.x, t = threadIdx.x;
    int base = b * SCAN_CHUNK + t * 4;
    int v[4];
    int s = 0;
#pragma unroll
    for (int k = 0; k < 4; k++) {
        int i = base + k;
        v[k] = (i < n) ? deg_i[i] : 0;
        s += v[k];
    }
    red[t] = s;
    __syncthreads();
    for (int d = 1; d < SCAN_TPB; d <<= 1) {
        int x = 0;
        if (t >= d) x = red[t - d];
        __syncthreads();
        if (t >= d) red[t] += x;
        __syncthreads();
    }
    int run = bsum[b] + red[t] - s;
#pragma unroll
    for (int k = 0; k < 4; k++) {
        int i = base + k;
        if (i < n) {
            off[i] = run;
            cursor[i] = run;
            dinv[i] = rsqrtf((float)v[k] + 1.0f);
            run += v[k];
        }
    }
    if (b == 0 && t == 0) off[n] = e;
}

// K5: counting-sort fill, XCD-localized (8 filtered passes; see R9 notes)
__global__ void k_fillpos(const int* __restrict__ src, const int* __restrict__ dst,
                          int* cursor, int* src_sorted, int e, int n) {
    int pass = blockIdx.x & 7;
    int i = (blockIdx.x >> 3) * blockDim.x + threadIdx.x;
    if (i >= e) return;
    int rlo = (int)(((long)n * pass) >> 3);
    int rhi = (int)(((long)n * (pass + 1)) >> 3);
    int d = dst[i];
    if (d >= rlo && d < rhi) {
        int p = atomicAdd(&cursor[d], 1);
        src_sorted[p] = src[i];
    }
}

// K6: layer-1 propagation as gather on raw 4-channel x; unroll x4 for MLP
__global__ void k_gather1(const int* __restrict__ off, const int* __restrict__ src_sorted,
                          const float* __restrict__ dinv, const float* __restrict__ x,
                          float* xp, int n) {
    int v = blockIdx.x * blockDim.x + threadIdx.x;
    if (v >= n) return;
    float dv = dinv[v];
    const float4* x4 = (const float4*)x;
    float4 xv = x4[v];
    float sl = dv * dv;
    float4 A = make_float4(sl * xv.x, sl * xv.y, sl * xv.z, sl * xv.w);
    float4 B = make_float4(0.f, 0.f, 0.f, 0.f);
    float4 C = make_float4(0.f, 0.f, 0.f, 0.f);
    float4 D = make_float4(0.f, 0.f, 0.f, 0.f);
    int e0 = off[v], e1 = off[v + 1];
    int e = e0;
    for (; e + 4 <= e1; e += 4) {
        int s0 = src_sorted[e], s1 = src_sorted[e + 1];
        int s2 = src_sorted[e + 2], s3 = src_sorted[e + 3];
        float n0 = dinv[s0] * dv, n1 = dinv[s1] * dv;
        float n2 = dinv[s2] * dv, n3 = dinv[s3] * dv;
        float4 r0 = x4[s0], r1 = x4[s1], r2 = x4[s2], r3 = x4[s3];
        A.x = fmaf(n0, r0.x, A.x); A.y = fmaf(n0, r0.y, A.y);
        A.z = fmaf(n0, r0.z, A.z); A.w = fmaf(n0, r0.w, A.w);
        B.x = fmaf(n1, r1.x, B.x); B.y = fmaf(n1, r1.y, B.y);
        B.z = fmaf(n1, r1.z, B.z); B.w = fmaf(n1, r1.w, B.w);
        C.x = fmaf(n2, r2.x, C.x); C.y = fmaf(n2, r2.y, C.y);
        C.z = fmaf(n2, r2.z, C.z); C.w = fmaf(n2, r2.w, C.w);
        D.x = fmaf(n3, r3.x, D.x); D.y = fmaf(n3, r3.y, D.y);
        D.z = fmaf(n3, r3.z, D.z); D.w = fmaf(n3, r3.w, D.w);
    }
    for (; e < e1; e++) {
        int s = src_sorted[e];
        float nm = dinv[s] * dv;
        float4 r = x4[s];
        A.x = fmaf(nm, r.x, A.x); A.y = fmaf(nm, r.y, A.y);
        A.z = fmaf(nm, r.z, A.z); A.w = fmaf(nm, r.w, A.w);
    }
    float4 o;
    o.x = (A.x + B.x) + (C.x + D.x);
    o.y = (A.y + B.y) + (C.y + D.y);
    o.z = (A.z + B.z) + (C.z + D.z);
    o.w = (A.w + B.w) + (C.w + D.w);
    ((float4*)xp)[v] = o;
}

// K7: f1 = relu(xp @ W1 + b1), output packed bf16 (2 ch per uint).
__global__ void k_f1(const float* __restrict__ xp, const float* __restrict__ W1,
                     const float* __restrict__ b1, unsigned* f1p, int n) {
    int i = blockIdx.x * blockDim.x + threadIdx.x;
    if (i >= n * 64) return;
    int v = i >> 6, cp = i & 63;
    int c0 = cp * 2, c1 = c0 + 1;
    float4 xv = *(const float4*)(xp + v * IN_C);
    float s0 = fmaf(xv.x, W1[c0],
               fmaf(xv.y, W1[HID + c0],
               fmaf(xv.z, W1[2 * HID + c0],
               fmaf(xv.w, W1[3 * HID + c0], b1[c0]))));
    float s1 = fmaf(xv.x, W1[c1],
               fmaf(xv.y, W1[HID + c1],
               fmaf(xv.z, W1[2 * HID + c1],
               fmaf(xv.w, W1[3 * HID + c1], b1[c1]))));
    s0 = s0 > 0.0f ? s0 : 0.0f;
    s1 = s1 > 0.0f ? s1 : 0.0f;
    f1p[i] = f2bf(s0) | (f2bf(s1) << 16);
}

// K8: layer-2 gather on bf16 rows; output acc2 packed bf16 (row = 256 B).
__global__ __launch_bounds__(256) void k_gather2(
        const int* __restrict__ off, const int* __restrict__ src_sorted,
        const float* __restrict__ dinv, const unsigned* __restrict__ f1p,
        unsigned* acc2b, int n) {
    int wv = threadIdx.x >> 6;           // wave id 0..3
    int ln = threadIdx.x & 63;           // lane: channels 2ln, 2ln+1
    int v = blockIdx.x * 4 + wv;
    if (v >= n) return;
    float dv = dinv[v];
    unsigned su = f1p[(size_t)v * 64 + ln];
    float sl = dv * dv;
    float ax = sl * bf_lo(su), ay = sl * bf_hi(su);
    float bx = 0.f, by = 0.f, cx = 0.f, cy = 0.f, dx = 0.f, dy = 0.f;
    int e0 = off[v], e1 = off[v + 1];
    int e = e0;
    for (; e + 4 <= e1; e += 4) {
        int s0 = src_sorted[e],     s1 = src_sorted[e + 1];
        int s2 = src_sorted[e + 2], s3 = src_sorted[e + 3];
        float n0 = dinv[s0] * dv, n1 = dinv[s1] * dv;
        float n2 = dinv[s2] * dv, n3 = dinv[s3] * dv;
        unsigned u0 = f1p[(size_t)s0 * 64 + ln];
        unsigned u1 = f1p[(size_t)s1 * 64 + ln];
        unsigned u2 = f1p[(size_t)s2 * 64 + ln];
        unsigned u3 = f1p[(size_t)s3 * 64 + ln];
        ax = fmaf(n0, bf_lo(u0), ax); ay = fmaf(n0, bf_hi(u0), ay);
        bx = fmaf(n1, bf_lo(u1), bx); by = fmaf(n1, bf_hi(u1), by);
        cx = fmaf(n2, bf_lo(u2), cx); cy = fmaf(n2, bf_hi(u2), cy);
        dx = fmaf(n3, bf_lo(u3), dx); dy = fmaf(n3, bf_hi(u3), dy);
    }
    for (; e < e1; e++) {
        int s = src_sorted[e];
        float nm = dinv[s] * dv;
        unsigned u = f1p[(size_t)s * 64 + ln];
        ax = fmaf(nm, bf_lo(u), ax); ay = fmaf(nm, bf_hi(u), ay);
    }
    float ox = (ax + bx) + (cx + dx);
    float oy = (ay + by) + (cy + dy);
    acc2b[(size_t)v * 64 + ln] = f2bf(ox) | (f2bf(oy) << 16);
}

// K8b: pre-swizzle W2 -> bf16 in MFMA B-fragment order.
// frag element (kk,nt,lane,j): value = W2[kk*32 + (lane>>4)*8 + j][nt*16 + (lane&15)]
__global__ void k_w2frag(const float* __restrict__ W2, unsigned short* w2f) {
    int i = blockIdx.x * blockDim.x + threadIdx.x;   // 0..16383
    if (i >= HID * HID) return;
    int j = i & 7, frag = i >> 3;
    int lane = frag & 63, blk = frag >> 6;           // blk = kk*8 + nt
    int kk = blk >> 3, nt = blk & 7;
    int quad = lane >> 4, nloc = lane & 15;
    int k = kk * 32 + quad * 8 + j;
    int c = nt * 16 + nloc;
    w2f[i] = (unsigned short)f2bf(W2[k * HID + c]);
}

// K9: MFMA GEMM + fused bias/ReLU/segment-pool.
// 4 waves/block; wave = 16 nodes x 128 ch = 8 C-tiles of 16x16, K=128 via 4
// mfma_f32_16x16x32_bf16. A from acc2b (16 rows x 64B lines, fully consumed);
// B from pre-swizzled w2f (coalesced uint4). C/D: col=lane&15, row=quad*4+reg.
__global__ __launch_bounds__(256) void k_mm2_pool(
        const unsigned* __restrict__ acc2b, const unsigned short* __restrict__ w2f,
        const float* __restrict__ b2, const int* __restrict__ batch,
        float* out, int n) {
    __shared__ int bch[64];
    int t = threadIdx.x;
    int w = t >> 6, lane = t & 63;
    int quad = lane >> 4, nloc = lane & 15;
    int v0 = blockIdx.x * 64;
    if (t < 64) {
        int v = v0 + t;
        bch[t] = (v < n) ? batch[v] : -1;
    }
    __syncthreads();

    int v0w = v0 + w * 16;
    int va = v0w + nloc;                 // A row for this lane
    if (va >= n) va = n - 1;             // clamp; garbage rows skipped in epilogue

    const uint4* A4 = (const uint4*)acc2b;      // row = 16 uint4
    const uint4* B4 = (const uint4*)w2f;        // frag blk = 64 uint4

    f32x4 acc[8];
#pragma unroll
    for (int nt = 0; nt < 8; nt++) acc[nt] = (f32x4){0.f, 0.f, 0.f, 0.f};

#pragma unroll
    for (int kk = 0; kk < 4; kk++) {
        FragU af;
        af.u = A4[(size_t)va * 16 + kk * 4 + quad];
#pragma unroll
        for (int nt = 0; nt < 8; nt++) {
            FragU bf;
            bf.u = B4[(kk * 8 + nt) * 64 + lane];
            acc[nt] = __builtin_amdgcn_mfma_f32_16x16x32_bf16(af.b, bf.b, acc[nt], 0, 0, 0);
        }
    }

    // epilogue: lane owns channel c = nt*16+nloc for 4 nodes (rows quad*4+reg)
    int b0 = bch[w * 16], b15 = bch[w * 16 + 15];
    if (b0 == b15 && b0 >= 0) {
        // fast path: whole 16-node stripe in one graph -> shfl-reduce quads
#pragma unroll
        for (int nt = 0; nt < 8; nt++) {
            float bias = b2[nt * 16 + nloc];
            float s = 0.f;
#pragma unroll
            for (int reg = 0; reg < 4; reg++) {
                float f = acc[nt][reg] + bias;
                s += f > 0.f ? f : 0.f;
            }
            s += __shfl_xor(s, 16, 64);
            s += __shfl_xor(s, 32, 64);
            if (lane < 16) atomicAdd(&out[b0 * HID + nt * 16 + lane], s);
        }
    } else {
        // slow path: per-lane run-accumulate over its 4 rows
#pragma unroll
        for (int nt = 0; nt < 8; nt++) {
            float bias = b2[nt * 16 + nloc];
            int cur = -1; float run = 0.f;
#pragma unroll
            for (int reg = 0; reg < 4; reg++) {
                int b = bch[w * 16 + quad * 4 + reg];
                if (b < 0) continue;
                float f = acc[nt][reg] + bias;
                f = f > 0.f ? f : 0.f;
                if (b != cur) {
                    if (cur >= 0) atomicAdd(&out[cur * HID + nt * 16 + nloc], run);
                    run = 0.f; cur = b;
                }
                run += f;
            }
            if (cur >= 0) atomicAdd(&out[cur * HID + nt * 16 + nloc], run);
        }
    }
}

// K10: out[b][c] /= max(cnt[b], 1)
__global__ void k_div(float* out, const int* __restrict__ cnt, int outsz) {
    int i = blockIdx.x * blockDim.x + threadIdx.x;
    if (i < outsz) {
        int b = i >> 7;
        float cf = (float)cnt[b];
        out[i] = out[i] / fmaxf(cf, 1.0f);
    }
}

extern "C" void kernel_launch(void* const* d_in, const int* in_sizes, int n_in,
                              void* d_out, int out_size, void* d_ws, size_t ws_size,
                              hipStream_t stream) {
    const float* x   = (const float*)d_in[0];
    const int* ei    = (const int*)d_in[1];   // [2, E] flat: src then dst
    const int* batch = (const int*)d_in[2];
    const float* W1  = (const float*)d_in[3];
    const float* b1  = (const float*)d_in[4];
    const float* W2  = (const float*)d_in[5];
    const float* b2  = (const float*)d_in[6];
    float* out = (float*)d_out;

    int n  = in_sizes[0] / IN_C;
    int e  = in_sizes[1] / 2;
    int bg = out_size / HID;
    const int* src = ei;
    const int* dst = ei + e;

    size_t off_b = 0;
    char* base = (char*)d_ws;
    auto carve = [&](size_t bytes) -> void* {
        void* p = base + off_b;
        off_b += (bytes + 255) & ~(size_t)255;
        return p;
    };
    int nbScan = (n + SCAN_CHUNK - 1) / SCAN_CHUNK;
    int*            deg_i      = (int*)carve((size_t)n * 4);
    int*            off        = (int*)carve((size_t)(n + 1) * 4);
    int*            cursor     = (int*)carve((size_t)n * 4);
    int*            src_sorted = (int*)carve((size_t)e * 4);
    float*          dinv       = (float*)carve((size_t)n * 4);
    int*            bsum       = (int*)carve((size_t)nbScan * 4);
    float*          xp         = (float*)carve((size_t)n * IN_C * 4);
    unsigned*       f1p        = (unsigned*)carve((size_t)n * 64 * 4);    // bf16-packed
    unsigned*       acc2b      = (unsigned*)carve((size_t)n * 64 * 4);    // bf16-packed
    unsigned short* w2f        = (unsigned short*)carve((size_t)HID * HID * 2);
    int*            cnt        = (int*)carve((size_t)bg * 4);
    (void)ws_size;

    int gN = (n + TPB - 1) / TPB;
    int gE = (e + TPB - 1) / TPB;

    k_init<<<gN, TPB, 0, stream>>>(deg_i, out, n, out_size);
    k_hist<<<gE, TPB, 0, stream>>>(dst, deg_i, e);
    k_cnt<<<1, 64, 0, stream>>>(batch, cnt, n, bg);
    k_scan_part<<<nbScan, SCAN_TPB, 0, stream>>>(deg_i, bsum, n);
    k_scan_bsum<<<1, 1024, 0, stream>>>(bsum, nbScan);
    k_scan_final<<<nbScan, SCAN_TPB, 0, stream>>>(deg_i, bsum, off, cursor, dinv, n, e);
    k_fillpos<<<gE * 8, TPB, 0, stream>>>(src, dst, cursor, src_sorted, e, n);
    k_w2frag<<<(HID * HID + TPB - 1) / TPB, TPB, 0, stream>>>(W2, w2f);
    k_gather1<<<gN, TPB, 0, stream>>>(off, src_sorted, dinv, x, xp, n);
    k_f1<<<(n * 64 + TPB - 1) / TPB, TPB, 0, stream>>>(xp, W1, b1, f1p, n);
    k_gather2<<<(n + 3) / 4, 256, 0, stream>>>(off, src_sorted, dinv, f1p, acc2b, n);
    k_mm2_pool<<<(n + 63) / 64, 256, 0, stream>>>(acc2b, w2f, b2, batch, out, n);
    k_div<<<(out_size + TPB - 1) / TPB, TPB, 0, stream>>>(out, cnt, out_size);
}